// Round 12
// baseline (101.335 us; speedup 1.0000x reference)
//
#include <hip/hip_runtime.h>
#include <math.h>

#define NB 4
#define NV 4096
#define DIN 3072
#define HD 64
#define CAP 80

typedef unsigned short u16;
typedef unsigned int u32;

__device__ __forceinline__ float lo16(u32 u) { return __uint_as_float(u << 16); }
__device__ __forceinline__ float hi16(u32 u) { return __uint_as_float(u & 0xffff0000u); }

// ---------------- encoder stage A: partial GEMV h_partial = stim @ W1 over k-chunks
__global__ __launch_bounds__(256) void enc_a_kernel(const float* __restrict__ stim,
                                                    const float* __restrict__ W1,
                                                    float* __restrict__ part) {
  int c = blockIdx.x;           // 24 k-chunks of 128
  int b = blockIdx.y;           // 4 batches
  int t = threadIdx.x;
  int j = t & 127, h = t >> 7;  // h: which 64-k half
  int k0 = c * 128 + h * 64;
  float acc = 0.f;
#pragma unroll 8
  for (int k = 0; k < 64; ++k)
    acc += stim[b * DIN + k0 + k] * W1[(size_t)(k0 + k) * 128 + j];
  part[((b * 24 + c) * 2 + h) * 128 + j] = acc;
}

// ---------------- encoder stage B: fixed-order reduce + LN + GELU + Linear(128->64)
__global__ __launch_bounds__(128) void enc_b_kernel(
    const float* __restrict__ part, const float* __restrict__ b1,
    const float* __restrict__ lng, const float* __restrict__ lnb,
    const float* __restrict__ W2, const float* __restrict__ b2, float* __restrict__ g) {
  int b = blockIdx.x;
  int t = threadIdx.x;
  float hv = 0.f;
  for (int c = 0; c < 48; ++c) hv += part[(b * 48 + c) * 128 + t];  // deterministic order
  hv += b1[t];
  __shared__ float act[128];
  __shared__ float red[128];
  __shared__ float s_mu, s_var;
  act[t] = hv;
  red[t] = hv;
  __syncthreads();
  for (int s = 64; s > 0; s >>= 1) {
    if (t < s) red[t] += red[t + s];
    __syncthreads();
  }
  if (t == 0) s_mu = red[0] * (1.f / 128.f);
  __syncthreads();
  float dv = act[t] - s_mu;
  red[t] = dv * dv;
  __syncthreads();
  for (int s = 64; s > 0; s >>= 1) {
    if (t < s) red[t] += red[t + s];
    __syncthreads();
  }
  if (t == 0) s_var = red[0] * (1.f / 128.f);
  __syncthreads();
  float y = (act[t] - s_mu) * rsqrtf(s_var + 1e-5f) * lng[t] + lnb[t];
  act[t] = 0.5f * y * (1.f + erff(y * 0.70710678118f));  // exact GELU
  __syncthreads();
  if (t < 64) {
    float a2 = 0.f;
    for (int k = 0; k < 128; ++k) a2 += act[k] * W2[k * 64 + t];
    g[b * 64 + t] = a2 + b2[t];
  }
}

// ---------------- deterministic neighbor-list build; shuffle prefix-scan; zero-filled tail
__global__ __launch_bounds__(256) void csr_kernel(const float* __restrict__ adj,
                                                  int* __restrict__ cnt, int* __restrict__ cols) {
  int row = blockIdx.x;
  int t = threadIdx.x;
  int l = t & 63, w = t >> 6;
  __shared__ int wtot[4];
  __shared__ int stot;
  const float4* p = (const float4*)(adj + (size_t)row * NV);
  float4 v0 = p[t], v1 = p[t + 256], v2 = p[t + 512], v3 = p[t + 768];
  int c = (v0.x > 0.f) + (v0.y > 0.f) + (v0.z > 0.f) + (v0.w > 0.f) +
          (v1.x > 0.f) + (v1.y > 0.f) + (v1.z > 0.f) + (v1.w > 0.f) +
          (v2.x > 0.f) + (v2.y > 0.f) + (v2.z > 0.f) + (v2.w > 0.f) +
          (v3.x > 0.f) + (v3.y > 0.f) + (v3.z > 0.f) + (v3.w > 0.f);
  int val = c;  // inclusive prefix within wave
#pragma unroll
  for (int off = 1; off < 64; off <<= 1) {
    int tmp = __shfl_up(val, off, 64);
    if (l >= off) val += tmp;
  }
  if (l == 63) wtot[w] = val;
  __syncthreads();
  int base = 0;
  for (int i = 0; i < w; ++i) base += wtot[i];
  if (t == 255) {
    int s = base + val;
    s = s > CAP ? CAP : s;
    cnt[row] = s;
    stot = s;
  }
  int o = base + (val - c);  // exclusive global prefix
  int* cr = cols + row * CAP;
#define EMIT(vv, jj) if ((vv) > 0.f) { if (o < CAP) cr[o] = (jj); ++o; }
  int j0 = t * 4, j1 = (t + 256) * 4, j2 = (t + 512) * 4, j3 = (t + 768) * 4;
  EMIT(v0.x, j0) EMIT(v0.y, j0 + 1) EMIT(v0.z, j0 + 2) EMIT(v0.w, j0 + 3)
  EMIT(v1.x, j1) EMIT(v1.y, j1 + 1) EMIT(v1.z, j1 + 2) EMIT(v1.w, j1 + 3)
  EMIT(v2.x, j2) EMIT(v2.y, j2 + 1) EMIT(v2.z, j2 + 2) EMIT(v2.w, j2 + 3)
  EMIT(v3.x, j3) EMIT(v3.y, j3 + 1) EMIT(v3.z, j3 + 2) EMIT(v3.w, j3 + 3)
#undef EMIT
  __syncthreads();
  if (t < CAP && t >= stot) cr[t] = 0;  // valid row id; p==0 masks it in attn
}

// ---------------- fused Wh(fp32) + Wh16 interleaved [n][b][64] = x@Wg ; Sk = x@Sw + sb
template <int LAYER>
__global__ __launch_bounds__(256) void whsk_kernel(
    const float* __restrict__ g, const float* __restrict__ emb, const float* __restrict__ xin,
    const float* __restrict__ Wg, const float* __restrict__ Sw, const float* __restrict__ Sb,
    float* __restrict__ Wh, u16* __restrict__ Wh16i, float* __restrict__ Sk) {
  __shared__ float wg[4096];
  __shared__ float sw[4096];
  __shared__ float xs[2048];
  __shared__ float sbs[64];
  int tid = threadIdx.x;
  for (int i = tid; i < 4096; i += 256) {
    wg[i] = Wg[i];
    sw[i] = Sw[i];
  }
  if (tid < 64) sbs[tid] = Sb[tid];
  int base = blockIdx.x * 32;  // 32 rows per block; all same batch
  int b = base >> 12;
  for (int i = tid; i < 2048; i += 256) {
    int rr = i >> 6, k = i & 63;
    int grow = base + rr;
    if (LAYER == 1) {
      int n = grow & (NV - 1);
      xs[i] = g[b * 64 + k] + emb[(size_t)n * 64 + k];
    } else {
      xs[i] = xin[(size_t)grow * 64 + k];
    }
  }
  __syncthreads();
  int cidx = tid & 63, r0 = tid >> 6;
  for (int rr = r0; rr < 32; rr += 4) {
    float aw = 0.f, as = 0.f;
#pragma unroll
    for (int k = 0; k < 64; ++k) {
      float xv = xs[rr * 64 + k];
      aw += xv * wg[k * 64 + cidx];
      as += xv * sw[k * 64 + cidx];
    }
    int grow = base + rr;
    int n = grow & (NV - 1);
    Wh[(size_t)grow * 64 + cidx] = aw;
    u32 u = __float_as_uint(aw);  // RNE bf16
    Wh16i[((size_t)n * 4 + b) * 64 + cidx] = (u16)((u + 0x7fffu + ((u >> 16) & 1u)) >> 16);
    Sk[(size_t)grow * 64 + cidx] = as + sbs[cidx];
  }
}

// ---------------- batch-merged sparse GAT attention: one wave per row n, all 4 batches.
// lane = b*16 + k16. Neighbor row m: ONE coalesced 512B load/wave (Wh16i[m][b][64]).
template <bool ELU1>
__global__ __launch_bounds__(256) void attn_kernel(
    const float* __restrict__ Wh, const u16* __restrict__ Wh16i, const float* __restrict__ Sk,
    const int* __restrict__ cnt, const int* __restrict__ cols, float* __restrict__ xout,
    const float* __restrict__ roW, const float* __restrict__ rob, float* __restrict__ out) {
  int tid = threadIdx.x;
  int lane = tid & 63;
  int w = tid >> 6;
  int n = __builtin_amdgcn_readfirstlane(blockIdx.x * 4 + w);
  int bb = lane >> 4;   // batch of this lane-group
  int k16 = lane & 15;  // column group (4 elems)
  int nn = __builtin_amdgcn_readfirstlane(cnt[n]);
  const int* cl = cols + n * CAP;

  // fp32 query: batch bb, elems [4k16, 4k16+4)
  float4 qv = *(const float4*)(Wh + (size_t)(bb * NV + n) * HD + 4 * k16);

  float s[5];
  s[0] = s[1] = s[2] = s[3] = s[4] = -1e30f;
  bool tail = (nn > 48);  // wave-uniform

#define SCORE_M(m)                                                                               \
  {                                                                                              \
    int mm = cl[m];                                                                              \
    uint2 V = *(const uint2*)(Wh16i + ((size_t)mm * 4 + bb) * HD + 4 * k16);                     \
    float t = qv.x * lo16(V.x) + qv.y * hi16(V.x) + qv.z * lo16(V.y) + qv.w * hi16(V.y);         \
    t += __shfl_xor(t, 1, 64);                                                                   \
    t += __shfl_xor(t, 2, 64);                                                                   \
    t += __shfl_xor(t, 4, 64);                                                                   \
    t += __shfl_xor(t, 8, 64);                                                                   \
    if (k16 == ((m)&15)) s[(m) >> 4] = ((m) < nn) ? t * 0.125f : -1e30f;                         \
  }
#pragma unroll
  for (int m = 0; m < 48; ++m) SCORE_M(m)
  if (tail) {
#pragma unroll
    for (int m = 48; m < CAP; ++m) SCORE_M(m)
  }
#undef SCORE_M

  // softmax per b-group (16 lanes); each j = jb*16+k16 counted once -> inv = 1/sum
  float mx = fmaxf(fmaxf(fmaxf(s[0], s[1]), fmaxf(s[2], s[3])), s[4]);
  mx = fmaxf(mx, __shfl_xor(mx, 1, 64));
  mx = fmaxf(mx, __shfl_xor(mx, 2, 64));
  mx = fmaxf(mx, __shfl_xor(mx, 4, 64));
  mx = fmaxf(mx, __shfl_xor(mx, 8, 64));
  float p[5];
  float sum = 0.f;
#pragma unroll
  for (int jb = 0; jb < 5; ++jb) {
    p[jb] = (jb * 16 + k16 < nn) ? __expf(s[jb] - mx) : 0.f;
    sum += p[jb];
  }
  sum += __shfl_xor(sum, 1, 64);
  sum += __shfl_xor(sum, 2, 64);
  sum += __shfl_xor(sum, 4, 64);
  sum += __shfl_xor(sum, 8, 64);
  float inv = 1.f / sum;

  // PV: re-load rows (L2-hot 2MB array), p broadcast within b-group via bpermute
  float ax = 0.f, ay = 0.f, az = 0.f, aw = 0.f;
  int gbase = lane & 48;  // b-group base lane
#define PV_M(m)                                                                                  \
  {                                                                                              \
    float pv = __shfl(p[(m) >> 4], gbase | ((m)&15), 64);                                        \
    int mm = cl[m];                                                                              \
    uint2 V = *(const uint2*)(Wh16i + ((size_t)mm * 4 + bb) * HD + 4 * k16);                     \
    ax = fmaf(pv, lo16(V.x), ax);                                                                \
    ay = fmaf(pv, hi16(V.x), ay);                                                                \
    az = fmaf(pv, lo16(V.y), az);                                                                \
    aw = fmaf(pv, hi16(V.y), aw);                                                                \
  }
#pragma unroll
  for (int m = 0; m < 48; ++m) PV_M(m)
  if (tail) {
#pragma unroll
    for (int m = 48; m < CAP; ++m) PV_M(m)
  }
#undef PV_M

  size_t obase = (size_t)(bb * NV + n) * HD + 4 * k16;
  float4 skv = *(const float4*)(Sk + obase);
  float vx = ax * inv, vy = ay * inv, vz = az * inv, vw = aw * inv;
  if (ELU1) {
    vx = (vx > 0.f ? vx : (__expf(vx) - 1.f)) + skv.x;
    vy = (vy > 0.f ? vy : (__expf(vy) - 1.f)) + skv.y;
    vz = (vz > 0.f ? vz : (__expf(vz) - 1.f)) + skv.z;
    vw = (vw > 0.f ? vw : (__expf(vw) - 1.f)) + skv.w;
    *(float4*)(xout + obase) = make_float4(vx, vy, vz, vw);
  } else {
    float4 ro = *(const float4*)(roW + 4 * k16);
    float ws = (vx + skv.x) * ro.x + (vy + skv.y) * ro.y +
               (vz + skv.z) * ro.z + (vw + skv.w) * ro.w;
    ws += __shfl_xor(ws, 1, 64);
    ws += __shfl_xor(ws, 2, 64);
    ws += __shfl_xor(ws, 4, 64);
    ws += __shfl_xor(ws, 8, 64);
    if (k16 == 0) out[bb * NV + n] = ws + rob[0];
  }
}

extern "C" void kernel_launch(void* const* d_in, const int* in_sizes, int n_in,
                              void* d_out, int out_size, void* d_ws, size_t ws_size,
                              hipStream_t stream) {
  const float* stim = (const float*)d_in[0];
  const float* adj  = (const float*)d_in[1];
  const float* W1   = (const float*)d_in[2];
  const float* b1   = (const float*)d_in[3];
  const float* lng  = (const float*)d_in[4];
  const float* lnb  = (const float*)d_in[5];
  const float* W2   = (const float*)d_in[6];
  const float* b2   = (const float*)d_in[7];
  const float* emb  = (const float*)d_in[8];
  const float* Wg1  = (const float*)d_in[9];
  const float* Wg2  = (const float*)d_in[10];
  const float* s1w  = (const float*)d_in[11];
  const float* s1b  = (const float*)d_in[12];
  const float* s2w  = (const float*)d_in[13];
  const float* s2b  = (const float*)d_in[14];
  const float* roW  = (const float*)d_in[15];
  const float* rob  = (const float*)d_in[16];
  float* out = (float*)d_out;

  char* ws = (char*)d_ws;
  float* g    = (float*)(ws + 0);          // 256 f32
  float* part = (float*)(ws + 4096);       // 96 KB
  int*   cnt  = (int*)(ws + 131072);       // 4096 ints
  int*   cols = (int*)(ws + 147456);       // 4096*80 ints = 1.25 MB
  float* Wh   = (float*)(ws + 1572864);    // 4 MB  [b*NV+n][64] fp32 (queries)
  float* Sk   = (float*)(ws + 5767168);    // 4 MB
  float* x1   = (float*)(ws + 9961472);    // 4 MB
  u16*   Wh16 = (u16*)(ws + 14155776);     // 2 MB  [n][b][64] bf16 interleaved

  enc_a_kernel<<<dim3(24, 4), dim3(256), 0, stream>>>(stim, W1, part);
  enc_b_kernel<<<dim3(4), dim3(128), 0, stream>>>(part, b1, lng, lnb, W2, b2, g);
  csr_kernel<<<dim3(NV), dim3(256), 0, stream>>>(adj, cnt, cols);
  whsk_kernel<1><<<dim3(NB * NV / 32), dim3(256), 0, stream>>>(g, emb, (const float*)nullptr,
                                                               Wg1, s1w, s1b, Wh, Wh16, Sk);
  attn_kernel<true><<<dim3(NV / 4), dim3(256), 0, stream>>>(Wh, Wh16, Sk, cnt, cols, x1,
                                                            roW, rob, (float*)nullptr);
  whsk_kernel<2><<<dim3(NB * NV / 32), dim3(256), 0, stream>>>(g, emb, x1, Wg2, s2w, s2b,
                                                               Wh, Wh16, Sk);
  attn_kernel<false><<<dim3(NV / 4), dim3(256), 0, stream>>>(Wh, Wh16, Sk, cnt, cols,
                                                             (float*)nullptr, roW, rob, out);
}

// Round 13
// 94.082 us; speedup vs baseline: 1.0771x; 1.0771x over previous
//
#include <hip/hip_runtime.h>
#include <math.h>

#define NB 4
#define NV 4096
#define DIN 3072
#define HD 64
#define CAP 80

typedef unsigned short u16;
typedef unsigned int u32;

__device__ __forceinline__ float lo16(u32 u) { return __uint_as_float(u << 16); }
__device__ __forceinline__ float hi16(u32 u) { return __uint_as_float(u & 0xffff0000u); }

// ---------------- encoder stage A: partial GEMV h_partial = stim @ W1 over k-chunks
__global__ __launch_bounds__(256) void enc_a_kernel(const float* __restrict__ stim,
                                                    const float* __restrict__ W1,
                                                    float* __restrict__ part) {
  int c = blockIdx.x;           // 24 k-chunks of 128
  int b = blockIdx.y;           // 4 batches
  int t = threadIdx.x;
  int j = t & 127, h = t >> 7;  // h: which 64-k half
  int k0 = c * 128 + h * 64;
  float acc = 0.f;
#pragma unroll 8
  for (int k = 0; k < 64; ++k)
    acc += stim[b * DIN + k0 + k] * W1[(size_t)(k0 + k) * 128 + j];
  part[((b * 24 + c) * 2 + h) * 128 + j] = acc;
}

// ---------------- encoder stage B: fixed-order reduce + LN + GELU + Linear(128->64)
__global__ __launch_bounds__(128) void enc_b_kernel(
    const float* __restrict__ part, const float* __restrict__ b1,
    const float* __restrict__ lng, const float* __restrict__ lnb,
    const float* __restrict__ W2, const float* __restrict__ b2, float* __restrict__ g) {
  int b = blockIdx.x;
  int t = threadIdx.x;
  float hv = 0.f;
  for (int c = 0; c < 48; ++c) hv += part[(b * 48 + c) * 128 + t];  // deterministic order
  hv += b1[t];
  __shared__ float act[128];
  __shared__ float red[128];
  __shared__ float s_mu, s_var;
  act[t] = hv;
  red[t] = hv;
  __syncthreads();
  for (int s = 64; s > 0; s >>= 1) {
    if (t < s) red[t] += red[t + s];
    __syncthreads();
  }
  if (t == 0) s_mu = red[0] * (1.f / 128.f);
  __syncthreads();
  float dv = act[t] - s_mu;
  red[t] = dv * dv;
  __syncthreads();
  for (int s = 64; s > 0; s >>= 1) {
    if (t < s) red[t] += red[t + s];
    __syncthreads();
  }
  if (t == 0) s_var = red[0] * (1.f / 128.f);
  __syncthreads();
  float y = (act[t] - s_mu) * rsqrtf(s_var + 1e-5f) * lng[t] + lnb[t];
  act[t] = 0.5f * y * (1.f + erff(y * 0.70710678118f));  // exact GELU
  __syncthreads();
  if (t < 64) {
    float a2 = 0.f;
    for (int k = 0; k < 128; ++k) a2 += act[k] * W2[k * 64 + t];
    g[b * 64 + t] = a2 + b2[t];
  }
}

// ---------------- deterministic neighbor-list build; shuffle prefix-scan; zero-filled tail
__global__ __launch_bounds__(256) void csr_kernel(const float* __restrict__ adj,
                                                  int* __restrict__ cnt, int* __restrict__ cols) {
  int row = blockIdx.x;
  int t = threadIdx.x;
  int l = t & 63, w = t >> 6;
  __shared__ int wtot[4];
  __shared__ int stot;
  const float4* p = (const float4*)(adj + (size_t)row * NV);
  float4 v0 = p[t], v1 = p[t + 256], v2 = p[t + 512], v3 = p[t + 768];
  int c = (v0.x > 0.f) + (v0.y > 0.f) + (v0.z > 0.f) + (v0.w > 0.f) +
          (v1.x > 0.f) + (v1.y > 0.f) + (v1.z > 0.f) + (v1.w > 0.f) +
          (v2.x > 0.f) + (v2.y > 0.f) + (v2.z > 0.f) + (v2.w > 0.f) +
          (v3.x > 0.f) + (v3.y > 0.f) + (v3.z > 0.f) + (v3.w > 0.f);
  int val = c;  // inclusive prefix within wave
#pragma unroll
  for (int off = 1; off < 64; off <<= 1) {
    int tmp = __shfl_up(val, off, 64);
    if (l >= off) val += tmp;
  }
  if (l == 63) wtot[w] = val;
  __syncthreads();
  int base = 0;
  for (int i = 0; i < w; ++i) base += wtot[i];
  if (t == 255) {
    int s = base + val;
    s = s > CAP ? CAP : s;
    cnt[row] = s;
    stot = s;
  }
  int o = base + (val - c);  // exclusive global prefix
  int* cr = cols + row * CAP;
#define EMIT(vv, jj) if ((vv) > 0.f) { if (o < CAP) cr[o] = (jj); ++o; }
  int j0 = t * 4, j1 = (t + 256) * 4, j2 = (t + 512) * 4, j3 = (t + 768) * 4;
  EMIT(v0.x, j0) EMIT(v0.y, j0 + 1) EMIT(v0.z, j0 + 2) EMIT(v0.w, j0 + 3)
  EMIT(v1.x, j1) EMIT(v1.y, j1 + 1) EMIT(v1.z, j1 + 2) EMIT(v1.w, j1 + 3)
  EMIT(v2.x, j2) EMIT(v2.y, j2 + 1) EMIT(v2.z, j2 + 2) EMIT(v2.w, j2 + 3)
  EMIT(v3.x, j3) EMIT(v3.y, j3 + 1) EMIT(v3.z, j3 + 2) EMIT(v3.w, j3 + 3)
#undef EMIT
  __syncthreads();
  if (t < CAP && t >= stot) cr[t] = 0;  // valid row id; p==0 masks it in attn
}

// ---------------- fused Wh(fp32 + bf16) = x@Wg and Sk = x@Sw + sb
template <int LAYER>
__global__ __launch_bounds__(256) void whsk_kernel(
    const float* __restrict__ g, const float* __restrict__ emb, const float* __restrict__ xin,
    const float* __restrict__ Wg, const float* __restrict__ Sw, const float* __restrict__ Sb,
    float* __restrict__ Wh, u16* __restrict__ Wh16, float* __restrict__ Sk) {
  __shared__ float wg[4096];
  __shared__ float sw[4096];
  __shared__ float xs[2048];
  __shared__ float sbs[64];
  int tid = threadIdx.x;
  for (int i = tid; i < 4096; i += 256) {
    wg[i] = Wg[i];
    sw[i] = Sw[i];
  }
  if (tid < 64) sbs[tid] = Sb[tid];
  int base = blockIdx.x * 32;  // 32 rows per block; all same batch
  int b = base >> 12;
  for (int i = tid; i < 2048; i += 256) {
    int rr = i >> 6, k = i & 63;
    int grow = base + rr;
    if (LAYER == 1) {
      int n = grow & (NV - 1);
      xs[i] = g[b * 64 + k] + emb[(size_t)n * 64 + k];
    } else {
      xs[i] = xin[(size_t)grow * 64 + k];
    }
  }
  __syncthreads();
  int cidx = tid & 63, r0 = tid >> 6;
  for (int rr = r0; rr < 32; rr += 4) {
    float aw = 0.f, as = 0.f;
#pragma unroll
    for (int k = 0; k < 64; ++k) {
      float xv = xs[rr * 64 + k];
      aw += xv * wg[k * 64 + cidx];
      as += xv * sw[k * 64 + cidx];
    }
    int grow = base + rr;
    Wh[(size_t)grow * 64 + cidx] = aw;
    u32 u = __float_as_uint(aw);  // RNE bf16
    Wh16[(size_t)grow * 64 + cidx] = (u16)((u + 0x7fffu + ((u >> 16) & 1u)) >> 16);
    Sk[(size_t)grow * 64 + cidx] = as + sbs[cidx];
  }
}

// ---------------- sparse GAT attention: wave/row, d-block layout, register-resident PV.
// q = lane>>4 owns output elems [16q,16q+16); gq = lane&15 owns neighbor slot gq of each block.
// Score rows stay in registers -> PV is pure VALU + 15-shuffle reduce-scatter. No PV reload
// except the rare tail (nn>48).
template <bool ELU1>
__global__ __launch_bounds__(256) void attn_kernel(
    const float* __restrict__ Wh, const u16* __restrict__ Wh16, const float* __restrict__ Sk,
    const int* __restrict__ cnt, const int* __restrict__ cols, float* __restrict__ xout,
    const float* __restrict__ roW, const float* __restrict__ rob, float* __restrict__ out) {
  int tid = threadIdx.x;
  int lane = tid & 63;
  int w = tid >> 6;
  int wid = blockIdx.x * 4 + w;  // = b*NV + n
  int b = wid >> 12;
  int n = __builtin_amdgcn_readfirstlane(wid & (NV - 1));
  const float* whbase = Wh + (size_t)b * (NV * HD);
  const u16* w16base = Wh16 + (size_t)b * (NV * HD);
  int nn = __builtin_amdgcn_readfirstlane(cnt[n]);
  const int* cl = cols + n * CAP;
  int q = lane >> 4;   // d-block
  int gq = lane & 15;  // neighbor slot

  // query fp32 elems [16q, 16q+16)
  const float* qrow = whbase + n * HD + 16 * q;
  float4 qv0 = *(const float4*)(qrow);
  float4 qv1 = *(const float4*)(qrow + 4);
  float4 qv2 = *(const float4*)(qrow + 8);
  float4 qv3 = *(const float4*)(qrow + 12);
  float skv = Sk[(size_t)wid * HD + lane];

  // score rows for main 3 blocks (bf16, elems [16q,16q+16) per lane)
  int m0 = cl[gq], m1 = cl[16 + gq], m2 = cl[32 + gq];
  const uint4* vr0 = (const uint4*)(w16base + (size_t)m0 * HD);
  const uint4* vr1 = (const uint4*)(w16base + (size_t)m1 * HD);
  const uint4* vr2 = (const uint4*)(w16base + (size_t)m2 * HD);
  uint4 A0 = vr0[2 * q], B0 = vr0[2 * q + 1];
  uint4 A1 = vr1[2 * q], B1 = vr1[2 * q + 1];
  uint4 A2 = vr2[2 * q], B2 = vr2[2 * q + 1];

  float Vf[3][16];
#define CONV(jb, A, B)                                                        \
  Vf[jb][0] = lo16(A.x); Vf[jb][1] = hi16(A.x); Vf[jb][2] = lo16(A.y);        \
  Vf[jb][3] = hi16(A.y); Vf[jb][4] = lo16(A.z); Vf[jb][5] = hi16(A.z);        \
  Vf[jb][6] = lo16(A.w); Vf[jb][7] = hi16(A.w); Vf[jb][8] = lo16(B.x);        \
  Vf[jb][9] = hi16(B.x); Vf[jb][10] = lo16(B.y); Vf[jb][11] = hi16(B.y);      \
  Vf[jb][12] = lo16(B.z); Vf[jb][13] = hi16(B.z); Vf[jb][14] = lo16(B.w);     \
  Vf[jb][15] = hi16(B.w);
  CONV(0, A0, B0) CONV(1, A1, B1) CONV(2, A2, B2)
#undef CONV

#define DOT(VF)                                                               \
  (qv0.x * VF[0] + qv0.y * VF[1] + qv0.z * VF[2] + qv0.w * VF[3] +            \
   qv1.x * VF[4] + qv1.y * VF[5] + qv1.z * VF[6] + qv1.w * VF[7] +            \
   qv2.x * VF[8] + qv2.y * VF[9] + qv2.z * VF[10] + qv2.w * VF[11] +          \
   qv3.x * VF[12] + qv3.y * VF[13] + qv3.z * VF[14] + qv3.w * VF[15])

  float s[5], p[5];
#pragma unroll
  for (int jb = 0; jb < 3; ++jb) {
    float t = DOT(Vf[jb]);
    t += __shfl_xor(t, 16, 64);  // reduce over q (4 lanes)
    t += __shfl_xor(t, 32, 64);
    s[jb] = (jb * 16 + gq < nn) ? t * 0.125f : -1e30f;
  }
  s[3] = -1e30f;
  s[4] = -1e30f;
  bool tail = (nn > 48);  // wave-uniform
  int m3 = 0, m4 = 0;
  if (tail) {
    m3 = cl[48 + gq];
    const uint4* vr3 = (const uint4*)(w16base + (size_t)m3 * HD);
    uint4 A = vr3[2 * q], B = vr3[2 * q + 1];
    float tf[16] = {lo16(A.x), hi16(A.x), lo16(A.y), hi16(A.y), lo16(A.z), hi16(A.z),
                    lo16(A.w), hi16(A.w), lo16(B.x), hi16(B.x), lo16(B.y), hi16(B.y),
                    lo16(B.z), hi16(B.z), lo16(B.w), hi16(B.w)};
    float t = DOT(tf);
    t += __shfl_xor(t, 16, 64);
    t += __shfl_xor(t, 32, 64);
    s[3] = (48 + gq < nn) ? t * 0.125f : -1e30f;
    if (nn > 64) {
      m4 = cl[64 + gq];
      const uint4* vr4 = (const uint4*)(w16base + (size_t)m4 * HD);
      uint4 A4 = vr4[2 * q], B4 = vr4[2 * q + 1];
      float tg[16] = {lo16(A4.x), hi16(A4.x), lo16(A4.y), hi16(A4.y), lo16(A4.z), hi16(A4.z),
                      lo16(A4.w), hi16(A4.w), lo16(B4.x), hi16(B4.x), lo16(B4.y), hi16(B4.y),
                      lo16(B4.z), hi16(B4.z), lo16(B4.w), hi16(B4.w)};
      float t4 = DOT(tg);
      t4 += __shfl_xor(t4, 16, 64);
      t4 += __shfl_xor(t4, 32, 64);
      s[4] = (64 + gq < nn) ? t4 * 0.125f : -1e30f;
    }
  }
#undef DOT

  // softmax over gq (16 lanes; values replicated across q); each j counted once
  float mx = fmaxf(fmaxf(fmaxf(s[0], s[1]), fmaxf(s[2], s[3])), s[4]);
  mx = fmaxf(mx, __shfl_xor(mx, 1, 64));
  mx = fmaxf(mx, __shfl_xor(mx, 2, 64));
  mx = fmaxf(mx, __shfl_xor(mx, 4, 64));
  mx = fmaxf(mx, __shfl_xor(mx, 8, 64));
  float sum = 0.f;
#pragma unroll
  for (int jb = 0; jb < 5; ++jb) {
    p[jb] = (jb * 16 + gq < nn) ? __expf(s[jb] - mx) : 0.f;
    sum += p[jb];
  }
  sum += __shfl_xor(sum, 1, 64);
  sum += __shfl_xor(sum, 2, 64);
  sum += __shfl_xor(sum, 4, 64);
  sum += __shfl_xor(sum, 8, 64);
  float inv = 1.f / sum;

  // PV main: pure VALU on register-resident rows
  float r[16];
#pragma unroll
  for (int e = 0; e < 16; ++e)
    r[e] = p[0] * Vf[0][e] + p[1] * Vf[1][e] + p[2] * Vf[2][e];

  // reduce-scatter over gq: lane gq ends with sum of elem gq -> d = 16q+gq = lane
  bool b8 = (gq & 8) != 0;
  float r8[8];
#pragma unroll
  for (int e = 0; e < 8; ++e) {
    float k = b8 ? r[e + 8] : r[e];
    float u = b8 ? r[e] : r[e + 8];
    r8[e] = k + __shfl_xor(u, 8, 64);
  }
  bool b4 = (gq & 4) != 0;
  float r4[4];
#pragma unroll
  for (int e = 0; e < 4; ++e) {
    float k = b4 ? r8[e + 4] : r8[e];
    float u = b4 ? r8[e] : r8[e + 4];
    r4[e] = k + __shfl_xor(u, 4, 64);
  }
  bool b2 = (gq & 2) != 0;
  float r2[2];
#pragma unroll
  for (int e = 0; e < 2; ++e) {
    float k = b2 ? r4[e + 2] : r4[e];
    float u = b2 ? r4[e] : r4[e + 2];
    r2[e] = k + __shfl_xor(u, 2, 64);
  }
  bool b1 = (gq & 1) != 0;
  float kk = b1 ? r2[1] : r2[0];
  float uu = b1 ? r2[0] : r2[1];
  float racc = kk + __shfl_xor(uu, 1, 64);

  // tail PV: reload rows (d = lane directly), p/m broadcast via readlane-style shfl
  if (tail) {
#pragma unroll
    for (int jj = 0; jj < 16; ++jj) {
      float pv = __shfl(p[3], jj, 64);
      int mm = __shfl(m3, jj, 64);
      racc = fmaf(pv, lo16((u32)w16base[(size_t)mm * HD + lane]), racc);
    }
    if (nn > 64) {
#pragma unroll
      for (int jj = 0; jj < 16; ++jj) {
        float pv = __shfl(p[4], jj, 64);
        int mm = __shfl(m4, jj, 64);
        racc = fmaf(pv, lo16((u32)w16base[(size_t)mm * HD + lane]), racc);
      }
    }
  }
  float acc = racc * inv;

  if (ELU1) {
    float e = acc > 0.f ? acc : (__expf(acc) - 1.f);
    xout[(size_t)wid * HD + lane] = e + skv;
  } else {
    float val = acc + skv;
    float wsum = val * roW[lane];
#pragma unroll
    for (int off = 32; off > 0; off >>= 1) wsum += __shfl_xor(wsum, off, 64);
    if (lane == 0) out[wid] = wsum + rob[0];
  }
}

extern "C" void kernel_launch(void* const* d_in, const int* in_sizes, int n_in,
                              void* d_out, int out_size, void* d_ws, size_t ws_size,
                              hipStream_t stream) {
  const float* stim = (const float*)d_in[0];
  const float* adj  = (const float*)d_in[1];
  const float* W1   = (const float*)d_in[2];
  const float* b1   = (const float*)d_in[3];
  const float* lng  = (const float*)d_in[4];
  const float* lnb  = (const float*)d_in[5];
  const float* W2   = (const float*)d_in[6];
  const float* b2   = (const float*)d_in[7];
  const float* emb  = (const float*)d_in[8];
  const float* Wg1  = (const float*)d_in[9];
  const float* Wg2  = (const float*)d_in[10];
  const float* s1w  = (const float*)d_in[11];
  const float* s1b  = (const float*)d_in[12];
  const float* s2w  = (const float*)d_in[13];
  const float* s2b  = (const float*)d_in[14];
  const float* roW  = (const float*)d_in[15];
  const float* rob  = (const float*)d_in[16];
  float* out = (float*)d_out;

  char* ws = (char*)d_ws;
  float* g    = (float*)(ws + 0);          // 256 f32
  float* part = (float*)(ws + 4096);       // 96 KB
  int*   cnt  = (int*)(ws + 131072);       // 4096 ints
  int*   cols = (int*)(ws + 147456);       // 4096*80 ints = 1.25 MB
  float* Wh   = (float*)(ws + 1572864);    // 4 MB
  float* Sk   = (float*)(ws + 5767168);    // 4 MB
  float* x1   = (float*)(ws + 9961472);    // 4 MB
  u16*   Wh16 = (u16*)(ws + 14155776);     // 2 MB  (total ~16.25 MB)

  enc_a_kernel<<<dim3(24, 4), dim3(256), 0, stream>>>(stim, W1, part);
  enc_b_kernel<<<dim3(4), dim3(128), 0, stream>>>(part, b1, lng, lnb, W2, b2, g);
  csr_kernel<<<dim3(NV), dim3(256), 0, stream>>>(adj, cnt, cols);
  whsk_kernel<1><<<dim3(NB * NV / 32), dim3(256), 0, stream>>>(g, emb, (const float*)nullptr,
                                                               Wg1, s1w, s1b, Wh, Wh16, Sk);
  attn_kernel<true><<<dim3(NB * NV / 4), dim3(256), 0, stream>>>(Wh, Wh16, Sk, cnt, cols, x1,
                                                                 roW, rob, (float*)nullptr);
  whsk_kernel<2><<<dim3(NB * NV / 32), dim3(256), 0, stream>>>(g, emb, x1, Wg2, s2w, s2b,
                                                               Wh, Wh16, Sk);
  attn_kernel<false><<<dim3(NB * NV / 4), dim3(256), 0, stream>>>(Wh, Wh16, Sk, cnt, cols,
                                                                  (float*)nullptr, roW, rob, out);
}

// Round 14
// 84.600 us; speedup vs baseline: 1.1978x; 1.1121x over previous
//
#include <hip/hip_runtime.h>
#include <math.h>

#define NB 4
#define NV 4096
#define DIN 3072
#define HD 64
#define CAP 80

typedef unsigned short u16;
typedef unsigned int u32;
typedef _Float16 h2 __attribute__((ext_vector_type(2)));

__device__ __forceinline__ float fdot2u(u32 v, u32 q, float c) {
#if __has_builtin(__builtin_amdgcn_fdot2)
  return __builtin_amdgcn_fdot2(__builtin_bit_cast(h2, v), __builtin_bit_cast(h2, q), c, false);
#else
  h2 a = __builtin_bit_cast(h2, v), b = __builtin_bit_cast(h2, q);
  return c + (float)a[0] * (float)b[0] + (float)a[1] * (float)b[1];
#endif
}

// ---------------- encoder stage A: partial GEMV h_partial = stim @ W1 over k-chunks
__global__ __launch_bounds__(256) void enc_a_kernel(const float* __restrict__ stim,
                                                    const float* __restrict__ W1,
                                                    float* __restrict__ part) {
  int c = blockIdx.x;           // 24 k-chunks of 128
  int b = blockIdx.y;           // 4 batches
  int t = threadIdx.x;
  int j = t & 127, h = t >> 7;  // h: which 64-k half
  int k0 = c * 128 + h * 64;
  float acc = 0.f;
#pragma unroll 8
  for (int k = 0; k < 64; ++k)
    acc += stim[b * DIN + k0 + k] * W1[(size_t)(k0 + k) * 128 + j];
  part[((b * 24 + c) * 2 + h) * 128 + j] = acc;
}

// ---------------- encoder stage B: fixed-order reduce + LN + GELU + Linear(128->64)
__global__ __launch_bounds__(128) void enc_b_kernel(
    const float* __restrict__ part, const float* __restrict__ b1,
    const float* __restrict__ lng, const float* __restrict__ lnb,
    const float* __restrict__ W2, const float* __restrict__ b2, float* __restrict__ g) {
  int b = blockIdx.x;
  int t = threadIdx.x;
  float hv = 0.f;
  for (int c = 0; c < 48; ++c) hv += part[(b * 48 + c) * 128 + t];  // deterministic order
  hv += b1[t];
  __shared__ float act[128];
  __shared__ float red[128];
  __shared__ float s_mu, s_var;
  act[t] = hv;
  red[t] = hv;
  __syncthreads();
  for (int s = 64; s > 0; s >>= 1) {
    if (t < s) red[t] += red[t + s];
    __syncthreads();
  }
  if (t == 0) s_mu = red[0] * (1.f / 128.f);
  __syncthreads();
  float dv = act[t] - s_mu;
  red[t] = dv * dv;
  __syncthreads();
  for (int s = 64; s > 0; s >>= 1) {
    if (t < s) red[t] += red[t + s];
    __syncthreads();
  }
  if (t == 0) s_var = red[0] * (1.f / 128.f);
  __syncthreads();
  float y = (act[t] - s_mu) * rsqrtf(s_var + 1e-5f) * lng[t] + lnb[t];
  act[t] = 0.5f * y * (1.f + erff(y * 0.70710678118f));  // exact GELU
  __syncthreads();
  if (t < 64) {
    float a2 = 0.f;
    for (int k = 0; k < 128; ++k) a2 += act[k] * W2[k * 64 + t];
    g[b * 64 + t] = a2 + b2[t];
  }
}

// ---------------- deterministic neighbor-list build; shuffle prefix-scan; zero-filled tail
__global__ __launch_bounds__(256) void csr_kernel(const float* __restrict__ adj,
                                                  int* __restrict__ cnt, int* __restrict__ cols) {
  int row = blockIdx.x;
  int t = threadIdx.x;
  int l = t & 63, w = t >> 6;
  __shared__ int wtot[4];
  __shared__ int stot;
  const float4* p = (const float4*)(adj + (size_t)row * NV);
  float4 v0 = p[t], v1 = p[t + 256], v2 = p[t + 512], v3 = p[t + 768];
  int c = (v0.x > 0.f) + (v0.y > 0.f) + (v0.z > 0.f) + (v0.w > 0.f) +
          (v1.x > 0.f) + (v1.y > 0.f) + (v1.z > 0.f) + (v1.w > 0.f) +
          (v2.x > 0.f) + (v2.y > 0.f) + (v2.z > 0.f) + (v2.w > 0.f) +
          (v3.x > 0.f) + (v3.y > 0.f) + (v3.z > 0.f) + (v3.w > 0.f);
  int val = c;  // inclusive prefix within wave
#pragma unroll
  for (int off = 1; off < 64; off <<= 1) {
    int tmp = __shfl_up(val, off, 64);
    if (l >= off) val += tmp;
  }
  if (l == 63) wtot[w] = val;
  __syncthreads();
  int base = 0;
  for (int i = 0; i < w; ++i) base += wtot[i];
  if (t == 255) {
    int s = base + val;
    s = s > CAP ? CAP : s;
    cnt[row] = s;
    stot = s;
  }
  int o = base + (val - c);  // exclusive global prefix
  int* cr = cols + row * CAP;
#define EMIT(vv, jj) if ((vv) > 0.f) { if (o < CAP) cr[o] = (jj); ++o; }
  int j0 = t * 4, j1 = (t + 256) * 4, j2 = (t + 512) * 4, j3 = (t + 768) * 4;
  EMIT(v0.x, j0) EMIT(v0.y, j0 + 1) EMIT(v0.z, j0 + 2) EMIT(v0.w, j0 + 3)
  EMIT(v1.x, j1) EMIT(v1.y, j1 + 1) EMIT(v1.z, j1 + 2) EMIT(v1.w, j1 + 3)
  EMIT(v2.x, j2) EMIT(v2.y, j2 + 1) EMIT(v2.z, j2 + 2) EMIT(v2.w, j2 + 3)
  EMIT(v3.x, j3) EMIT(v3.y, j3 + 1) EMIT(v3.z, j3 + 2) EMIT(v3.w, j3 + 3)
#undef EMIT
  __syncthreads();
  if (t < CAP && t >= stot) cr[t] = 0;  // valid row id; p==0 masks it in attn
}

// ---------------- fused Wh(fp32 + f16) = x@Wg and Sk = x@Sw + sb
template <int LAYER>
__global__ __launch_bounds__(256) void whsk_kernel(
    const float* __restrict__ g, const float* __restrict__ emb, const float* __restrict__ xin,
    const float* __restrict__ Wg, const float* __restrict__ Sw, const float* __restrict__ Sb,
    float* __restrict__ Wh, u16* __restrict__ Whh, float* __restrict__ Sk) {
  __shared__ float wg[4096];
  __shared__ float sw[4096];
  __shared__ float xs[2048];
  __shared__ float sbs[64];
  int tid = threadIdx.x;
  for (int i = tid; i < 4096; i += 256) {
    wg[i] = Wg[i];
    sw[i] = Sw[i];
  }
  if (tid < 64) sbs[tid] = Sb[tid];
  int base = blockIdx.x * 32;  // 32 rows per block; all same batch
  int b = base >> 12;
  for (int i = tid; i < 2048; i += 256) {
    int rr = i >> 6, k = i & 63;
    int grow = base + rr;
    if (LAYER == 1) {
      int n = grow & (NV - 1);
      xs[i] = g[b * 64 + k] + emb[(size_t)n * 64 + k];
    } else {
      xs[i] = xin[(size_t)grow * 64 + k];
    }
  }
  __syncthreads();
  int cidx = tid & 63, r0 = tid >> 6;
  for (int rr = r0; rr < 32; rr += 4) {
    float aw = 0.f, as = 0.f;
#pragma unroll
    for (int k = 0; k < 64; ++k) {
      float xv = xs[rr * 64 + k];
      aw += xv * wg[k * 64 + cidx];
      as += xv * sw[k * 64 + cidx];
    }
    int grow = base + rr;
    Wh[(size_t)grow * 64 + cidx] = aw;
    _Float16 hv = (_Float16)aw;  // RNE f32->f16
    Whh[(size_t)grow * 64 + cidx] = __builtin_bit_cast(u16, hv);
    Sk[(size_t)grow * 64 + cidx] = as + sbs[cidx];
  }
}

// ---------------- sparse GAT attention: wave/row; XCD-pinned; f16 fdot2 scores; fp32 PV
// blockIdx swizzle: bid&7 = XCD slot x; XCD x serves batch x>>1, row-half x&1.
// Per-XCD gather hot set: Whh[b] (0.5MB) + Wh[b] (1MB) -> L2-resident.
template <bool ELU1>
__global__ __launch_bounds__(256) void attn_kernel(
    const float* __restrict__ Wh, const u16* __restrict__ Whh, const float* __restrict__ Sk,
    const int* __restrict__ cnt, const int* __restrict__ cols, float* __restrict__ xout,
    const float* __restrict__ roW, const float* __restrict__ rob, float* __restrict__ out) {
  int tid = threadIdx.x;
  int lane = tid & 63;
  int w = tid >> 6;
  int bid = blockIdx.x;
  int x = bid & 7;       // XCD slot
  int gidx = bid >> 3;   // 0..511
  int b = x >> 1;        // batch pinned to XCD pair
  int n = __builtin_amdgcn_readfirstlane((x & 1) * 2048 + gidx * 4 + w);
  int wid = b * NV + n;
  const float* whbase = Wh + (size_t)b * (NV * HD);
  const u16* whhbase = Whh + (size_t)b * (NV * HD);
  int nn = __builtin_amdgcn_readfirstlane(cnt[n]);
  const int* cl = cols + n * CAP;
  int q = lane & 3;    // lane-in-quad
  int gq = lane >> 2;  // quad 0..15

  // f16 query: elems [8q,8q+8) and [32+8q,32+8q+8) as packed half2 words
  const uint4* qr = (const uint4*)(whhbase + (size_t)n * HD);
  uint4 QA = qr[q];
  uint4 QB = qr[q + 4];

  float s[5], p[5];
#define SCORE_BLOCK(jb)                                                                          \
  {                                                                                              \
    int j = (jb) * 16 + gq;                                                                      \
    int m = cl[j];                                                                               \
    const uint4* vr = (const uint4*)(whhbase + (size_t)m * HD);                                  \
    uint4 A = vr[q];                                                                             \
    uint4 B = vr[q + 4];                                                                         \
    float t = 0.f;                                                                               \
    t = fdot2u(A.x, QA.x, t);                                                                    \
    t = fdot2u(A.y, QA.y, t);                                                                    \
    t = fdot2u(A.z, QA.z, t);                                                                    \
    t = fdot2u(A.w, QA.w, t);                                                                    \
    t = fdot2u(B.x, QB.x, t);                                                                    \
    t = fdot2u(B.y, QB.y, t);                                                                    \
    t = fdot2u(B.z, QB.z, t);                                                                    \
    t = fdot2u(B.w, QB.w, t);                                                                    \
    t += __shfl_xor(t, 1, 64);                                                                   \
    t += __shfl_xor(t, 2, 64);                                                                   \
    s[jb] = (j < nn) ? t * 0.125f : -1e30f;                                                      \
  }

  // first 3 blocks straight-line (cols tail zero-filled -> m=0 dummy, masked by j<nn)
  SCORE_BLOCK(0)
  SCORE_BLOCK(1)
  SCORE_BLOCK(2)
  s[3] = -1e30f;
  s[4] = -1e30f;
  bool tail = (nn > 48);  // wave-uniform
  if (tail) {
    SCORE_BLOCK(3)
    SCORE_BLOCK(4)
  }
#undef SCORE_BLOCK

  // softmax: 4-step quad-class reduces (s,p quad-uniform); each j counted once -> inv = 1/sum
  float mx = fmaxf(fmaxf(fmaxf(s[0], s[1]), fmaxf(s[2], s[3])), s[4]);
  mx = fmaxf(mx, __shfl_xor(mx, 4, 64));
  mx = fmaxf(mx, __shfl_xor(mx, 8, 64));
  mx = fmaxf(mx, __shfl_xor(mx, 16, 64));
  mx = fmaxf(mx, __shfl_xor(mx, 32, 64));
  float sum = 0.f;
#pragma unroll
  for (int jb = 0; jb < 5; ++jb) {
    p[jb] = (jb * 16 + gq < nn) ? __expf(s[jb] - mx) : 0.f;
    sum += p[jb];
  }
  sum += __shfl_xor(sum, 4, 64);
  sum += __shfl_xor(sum, 8, 64);
  sum += __shfl_xor(sum, 16, 64);
  sum += __shfl_xor(sum, 32, 64);
  float inv = 1.f / sum;

  // PV: fp32 rows (best measured), guard per 16-block; 4 independent acc chains
  float a0 = 0.f, a1 = 0.f, a2 = 0.f, a3 = 0.f;
#define RL(jb, jj) __int_as_float(__builtin_amdgcn_readlane(__float_as_int(p[jb]), 4 * (jj)))
#define PV_ITER(jb, jj, accv)                                                                    \
  {                                                                                              \
    float pv = RL(jb, jj);                                                                       \
    int m = cl[(jb) * 16 + (jj)];                                                                \
    accv = fmaf(pv, whbase[(size_t)m * HD + lane], accv);                                        \
  }
#define PV_BLOCK(jb)                                                                             \
  PV_ITER(jb, 0, a0) PV_ITER(jb, 1, a1) PV_ITER(jb, 2, a2) PV_ITER(jb, 3, a3)                    \
  PV_ITER(jb, 4, a0) PV_ITER(jb, 5, a1) PV_ITER(jb, 6, a2) PV_ITER(jb, 7, a3)                    \
  PV_ITER(jb, 8, a0) PV_ITER(jb, 9, a1) PV_ITER(jb, 10, a2) PV_ITER(jb, 11, a3)                  \
  PV_ITER(jb, 12, a0) PV_ITER(jb, 13, a1) PV_ITER(jb, 14, a2) PV_ITER(jb, 15, a3)
  PV_BLOCK(0)
  PV_BLOCK(1)
  PV_BLOCK(2)
  if (tail) {
    PV_BLOCK(3)
    PV_BLOCK(4)
  }
#undef PV_BLOCK
#undef PV_ITER
#undef RL
  float acc = ((a0 + a1) + (a2 + a3)) * inv;

  float skv = Sk[(size_t)wid * HD + lane];
  if (ELU1) {
    float e = acc > 0.f ? acc : (__expf(acc) - 1.f);
    xout[(size_t)wid * HD + lane] = e + skv;
  } else {
    float val = acc + skv;
    float wsum = val * roW[lane];
#pragma unroll
    for (int off = 32; off > 0; off >>= 1) wsum += __shfl_xor(wsum, off, 64);
    if (lane == 0) out[wid] = wsum + rob[0];
  }
}

extern "C" void kernel_launch(void* const* d_in, const int* in_sizes, int n_in,
                              void* d_out, int out_size, void* d_ws, size_t ws_size,
                              hipStream_t stream) {
  const float* stim = (const float*)d_in[0];
  const float* adj  = (const float*)d_in[1];
  const float* W1   = (const float*)d_in[2];
  const float* b1   = (const float*)d_in[3];
  const float* lng  = (const float*)d_in[4];
  const float* lnb  = (const float*)d_in[5];
  const float* W2   = (const float*)d_in[6];
  const float* b2   = (const float*)d_in[7];
  const float* emb  = (const float*)d_in[8];
  const float* Wg1  = (const float*)d_in[9];
  const float* Wg2  = (const float*)d_in[10];
  const float* s1w  = (const float*)d_in[11];
  const float* s1b  = (const float*)d_in[12];
  const float* s2w  = (const float*)d_in[13];
  const float* s2b  = (const float*)d_in[14];
  const float* roW  = (const float*)d_in[15];
  const float* rob  = (const float*)d_in[16];
  float* out = (float*)d_out;

  char* ws = (char*)d_ws;
  float* g    = (float*)(ws + 0);          // 256 f32
  float* part = (float*)(ws + 4096);       // 96 KB
  int*   cnt  = (int*)(ws + 131072);       // 4096 ints
  int*   cols = (int*)(ws + 147456);       // 4096*80 ints = 1.25 MB
  float* Wh   = (float*)(ws + 1572864);    // 4 MB  fp32 (PV + queries-precision source)
  float* Sk   = (float*)(ws + 5767168);    // 4 MB
  float* x1   = (float*)(ws + 9961472);    // 4 MB
  u16*   Whh  = (u16*)(ws + 14155776);     // 2 MB  f16 (score gathers)

  enc_a_kernel<<<dim3(24, 4), dim3(256), 0, stream>>>(stim, W1, part);
  enc_b_kernel<<<dim3(4), dim3(128), 0, stream>>>(part, b1, lng, lnb, W2, b2, g);
  csr_kernel<<<dim3(NV), dim3(256), 0, stream>>>(adj, cnt, cols);
  whsk_kernel<1><<<dim3(NB * NV / 32), dim3(256), 0, stream>>>(g, emb, (const float*)nullptr,
                                                               Wg1, s1w, s1b, Wh, Whh, Sk);
  attn_kernel<true><<<dim3(NB * NV / 4), dim3(256), 0, stream>>>(Wh, Whh, Sk, cnt, cols, x1,
                                                                 roW, rob, (float*)nullptr);
  whsk_kernel<2><<<dim3(NB * NV / 32), dim3(256), 0, stream>>>(g, emb, x1, Wg2, s2w, s2b,
                                                               Wh, Whh, Sk);
  attn_kernel<false><<<dim3(NB * NV / 4), dim3(256), 0, stream>>>(Wh, Whh, Sk, cnt, cols,
                                                                  (float*)nullptr, roW, rob, out);
}

// Round 15
// 83.533 us; speedup vs baseline: 1.2131x; 1.0128x over previous
//
#include <hip/hip_runtime.h>
#include <math.h>

#define NB 4
#define NV 4096
#define DIN 3072
#define HD 64
#define CAP 80

typedef unsigned short u16;
typedef unsigned int u32;
typedef _Float16 h2 __attribute__((ext_vector_type(2)));

__device__ __forceinline__ float fdot2u(u32 v, u32 q, float c) {
#if __has_builtin(__builtin_amdgcn_fdot2)
  return __builtin_amdgcn_fdot2(__builtin_bit_cast(h2, v), __builtin_bit_cast(h2, q), c, false);
#else
  h2 a = __builtin_bit_cast(h2, v), b = __builtin_bit_cast(h2, q);
  return c + (float)a[0] * (float)b[0] + (float)a[1] * (float)b[1];
#endif
}

// ---------------- encoder stage A: partial GEMV h_partial = stim @ W1 over k-chunks
__global__ __launch_bounds__(256) void enc_a_kernel(const float* __restrict__ stim,
                                                    const float* __restrict__ W1,
                                                    float* __restrict__ part) {
  int c = blockIdx.x;           // 24 k-chunks of 128
  int b = blockIdx.y;           // 4 batches
  int t = threadIdx.x;
  int j = t & 127, h = t >> 7;  // h: which 64-k half
  int k0 = c * 128 + h * 64;
  float acc = 0.f;
#pragma unroll 8
  for (int k = 0; k < 64; ++k)
    acc += stim[b * DIN + k0 + k] * W1[(size_t)(k0 + k) * 128 + j];
  part[((b * 24 + c) * 2 + h) * 128 + j] = acc;
}

// ---------------- encoder stage B: fixed-order reduce + LN + GELU + Linear(128->64)
__global__ __launch_bounds__(128) void enc_b_kernel(
    const float* __restrict__ part, const float* __restrict__ b1,
    const float* __restrict__ lng, const float* __restrict__ lnb,
    const float* __restrict__ W2, const float* __restrict__ b2, float* __restrict__ g) {
  int b = blockIdx.x;
  int t = threadIdx.x;
  float hv = 0.f;
  for (int c = 0; c < 48; ++c) hv += part[(b * 48 + c) * 128 + t];  // deterministic order
  hv += b1[t];
  __shared__ float act[128];
  __shared__ float red[128];
  __shared__ float s_mu, s_var;
  act[t] = hv;
  red[t] = hv;
  __syncthreads();
  for (int s = 64; s > 0; s >>= 1) {
    if (t < s) red[t] += red[t + s];
    __syncthreads();
  }
  if (t == 0) s_mu = red[0] * (1.f / 128.f);
  __syncthreads();
  float dv = act[t] - s_mu;
  red[t] = dv * dv;
  __syncthreads();
  for (int s = 64; s > 0; s >>= 1) {
    if (t < s) red[t] += red[t + s];
    __syncthreads();
  }
  if (t == 0) s_var = red[0] * (1.f / 128.f);
  __syncthreads();
  float y = (act[t] - s_mu) * rsqrtf(s_var + 1e-5f) * lng[t] + lnb[t];
  act[t] = 0.5f * y * (1.f + erff(y * 0.70710678118f));  // exact GELU
  __syncthreads();
  if (t < 64) {
    float a2 = 0.f;
    for (int k = 0; k < 128; ++k) a2 += act[k] * W2[k * 64 + t];
    g[b * 64 + t] = a2 + b2[t];
  }
}

// ---------------- deterministic neighbor-list build; shuffle prefix-scan; zero-filled tail
__global__ __launch_bounds__(256) void csr_kernel(const float* __restrict__ adj,
                                                  int* __restrict__ cnt, int* __restrict__ cols) {
  int row = blockIdx.x;
  int t = threadIdx.x;
  int l = t & 63, w = t >> 6;
  __shared__ int wtot[4];
  __shared__ int stot;
  const float4* p = (const float4*)(adj + (size_t)row * NV);
  float4 v0 = p[t], v1 = p[t + 256], v2 = p[t + 512], v3 = p[t + 768];
  int c = (v0.x > 0.f) + (v0.y > 0.f) + (v0.z > 0.f) + (v0.w > 0.f) +
          (v1.x > 0.f) + (v1.y > 0.f) + (v1.z > 0.f) + (v1.w > 0.f) +
          (v2.x > 0.f) + (v2.y > 0.f) + (v2.z > 0.f) + (v2.w > 0.f) +
          (v3.x > 0.f) + (v3.y > 0.f) + (v3.z > 0.f) + (v3.w > 0.f);
  int val = c;  // inclusive prefix within wave
#pragma unroll
  for (int off = 1; off < 64; off <<= 1) {
    int tmp = __shfl_up(val, off, 64);
    if (l >= off) val += tmp;
  }
  if (l == 63) wtot[w] = val;
  __syncthreads();
  int base = 0;
  for (int i = 0; i < w; ++i) base += wtot[i];
  if (t == 255) {
    int s = base + val;
    s = s > CAP ? CAP : s;
    cnt[row] = s;
    stot = s;
  }
  int o = base + (val - c);  // exclusive global prefix
  int* cr = cols + row * CAP;
#define EMIT(vv, jj) if ((vv) > 0.f) { if (o < CAP) cr[o] = (jj); ++o; }
  int j0 = t * 4, j1 = (t + 256) * 4, j2 = (t + 512) * 4, j3 = (t + 768) * 4;
  EMIT(v0.x, j0) EMIT(v0.y, j0 + 1) EMIT(v0.z, j0 + 2) EMIT(v0.w, j0 + 3)
  EMIT(v1.x, j1) EMIT(v1.y, j1 + 1) EMIT(v1.z, j1 + 2) EMIT(v1.w, j1 + 3)
  EMIT(v2.x, j2) EMIT(v2.y, j2 + 1) EMIT(v2.z, j2 + 2) EMIT(v2.w, j2 + 3)
  EMIT(v3.x, j3) EMIT(v3.y, j3 + 1) EMIT(v3.z, j3 + 2) EMIT(v3.w, j3 + 3)
#undef EMIT
  __syncthreads();
  if (t < CAP && t >= stot) cr[t] = 0;  // valid row id; p==0 masks it in attn
}

// ---------------- fused Wh(fp32 + f16) = x@Wg and Sk = x@Sw + sb
template <int LAYER>
__global__ __launch_bounds__(256) void whsk_kernel(
    const float* __restrict__ g, const float* __restrict__ emb, const float* __restrict__ xin,
    const float* __restrict__ Wg, const float* __restrict__ Sw, const float* __restrict__ Sb,
    float* __restrict__ Wh, u16* __restrict__ Whh, float* __restrict__ Sk) {
  __shared__ float wg[4096];
  __shared__ float sw[4096];
  __shared__ float xs[2048];
  __shared__ float sbs[64];
  int tid = threadIdx.x;
  for (int i = tid; i < 4096; i += 256) {
    wg[i] = Wg[i];
    sw[i] = Sw[i];
  }
  if (tid < 64) sbs[tid] = Sb[tid];
  int base = blockIdx.x * 32;  // 32 rows per block; all same batch
  int b = base >> 12;
  for (int i = tid; i < 2048; i += 256) {
    int rr = i >> 6, k = i & 63;
    int grow = base + rr;
    if (LAYER == 1) {
      int n = grow & (NV - 1);
      xs[i] = g[b * 64 + k] + emb[(size_t)n * 64 + k];
    } else {
      xs[i] = xin[(size_t)grow * 64 + k];
    }
  }
  __syncthreads();
  int cidx = tid & 63, r0 = tid >> 6;
  for (int rr = r0; rr < 32; rr += 4) {
    float aw = 0.f, as = 0.f;
#pragma unroll
    for (int k = 0; k < 64; ++k) {
      float xv = xs[rr * 64 + k];
      aw += xv * wg[k * 64 + cidx];
      as += xv * sw[k * 64 + cidx];
    }
    int grow = base + rr;
    Wh[(size_t)grow * 64 + cidx] = aw;
    _Float16 hv = (_Float16)aw;  // RNE f32->f16
    Whh[(size_t)grow * 64 + cidx] = __builtin_bit_cast(u16, hv);
    Sk[(size_t)grow * 64 + cidx] = as + sbs[cidx];
  }
}

// ---------------- sparse GAT attention: wave/row; XCD-pinned; f16 fdot2 scores;
// PV via 4-row-wide float4 gathers (48 loads -> 12). lane l covers row-group l>>4,
// elems [4*(l&15), +4).
template <bool ELU1>
__global__ __launch_bounds__(256) void attn_kernel(
    const float* __restrict__ Wh, const u16* __restrict__ Whh, const float* __restrict__ Sk,
    const int* __restrict__ cnt, const int* __restrict__ cols, float* __restrict__ xout,
    const float* __restrict__ roW, const float* __restrict__ rob, float* __restrict__ out) {
  int tid = threadIdx.x;
  int lane = tid & 63;
  int w = tid >> 6;
  int bid = blockIdx.x;
  int x = bid & 7;       // XCD slot
  int gidx = bid >> 3;   // 0..511
  int b = x >> 1;        // batch pinned to XCD pair
  int n = __builtin_amdgcn_readfirstlane((x & 1) * 2048 + gidx * 4 + w);
  int wid = b * NV + n;
  const float* whbase = Wh + (size_t)b * (NV * HD);
  const u16* whhbase = Whh + (size_t)b * (NV * HD);
  int nn = __builtin_amdgcn_readfirstlane(cnt[n]);
  const int* cl = cols + n * CAP;
  int q = lane & 3;    // lane-in-quad
  int gq = lane >> 2;  // quad 0..15

  // f16 query: packed half2 words, elems [8q,8q+8) and [32+8q,...)
  const uint4* qr = (const uint4*)(whhbase + (size_t)n * HD);
  uint4 QA = qr[q];
  uint4 QB = qr[q + 4];

  float s[5], p[5];
  int mS[5];
#define SCORE_BLOCK(jb)                                                                          \
  {                                                                                              \
    int j = (jb) * 16 + gq;                                                                      \
    mS[jb] = cl[j];                                                                              \
    const uint4* vr = (const uint4*)(whhbase + (size_t)mS[jb] * HD);                             \
    uint4 A = vr[q];                                                                             \
    uint4 B = vr[q + 4];                                                                         \
    float t = 0.f;                                                                               \
    t = fdot2u(A.x, QA.x, t);                                                                    \
    t = fdot2u(A.y, QA.y, t);                                                                    \
    t = fdot2u(A.z, QA.z, t);                                                                    \
    t = fdot2u(A.w, QA.w, t);                                                                    \
    t = fdot2u(B.x, QB.x, t);                                                                    \
    t = fdot2u(B.y, QB.y, t);                                                                    \
    t = fdot2u(B.z, QB.z, t);                                                                    \
    t = fdot2u(B.w, QB.w, t);                                                                    \
    t += __shfl_xor(t, 1, 64);                                                                   \
    t += __shfl_xor(t, 2, 64);                                                                   \
    s[jb] = (j < nn) ? t * 0.125f : -1e30f;                                                      \
  }

  SCORE_BLOCK(0)
  SCORE_BLOCK(1)
  SCORE_BLOCK(2)
  s[3] = -1e30f;
  s[4] = -1e30f;
  mS[3] = 0;
  mS[4] = 0;
  bool tail = (nn > 48);  // wave-uniform
  if (tail) {
    SCORE_BLOCK(3)
    SCORE_BLOCK(4)
  }
#undef SCORE_BLOCK

  // softmax: 4-step quad-class reduces; each j counted once -> inv = 1/sum
  float mx = fmaxf(fmaxf(fmaxf(s[0], s[1]), fmaxf(s[2], s[3])), s[4]);
  mx = fmaxf(mx, __shfl_xor(mx, 4, 64));
  mx = fmaxf(mx, __shfl_xor(mx, 8, 64));
  mx = fmaxf(mx, __shfl_xor(mx, 16, 64));
  mx = fmaxf(mx, __shfl_xor(mx, 32, 64));
  float sum = 0.f;
#pragma unroll
  for (int jb = 0; jb < 5; ++jb) {
    p[jb] = (jb * 16 + gq < nn) ? __expf(s[jb] - mx) : 0.f;
    sum += p[jb];
  }
  sum += __shfl_xor(sum, 4, 64);
  sum += __shfl_xor(sum, 8, 64);
  sum += __shfl_xor(sum, 16, 64);
  sum += __shfl_xor(sum, 32, 64);
  float inv = 1.f / sum;

  // PV: 4 rows per float4-gather. Iter i covers rows 4i+(lane>>4); p/m via bpermute.
  int base4 = 4 * (lane >> 4);
  int e4 = 4 * (lane & 15);
  float4 acc4 = make_float4(0.f, 0.f, 0.f, 0.f);
#define PV_GATHER(i, jb)                                                                         \
  {                                                                                              \
    int srcl = (16 * (i) + base4) & 63;                                                          \
    float pv = __shfl(p[jb], srcl, 64);                                                          \
    int mm = __shfl(mS[jb], srcl, 64);                                                           \
    float4 v = *(const float4*)(whbase + (size_t)mm * HD + e4);                                  \
    acc4.x = fmaf(pv, v.x, acc4.x);                                                              \
    acc4.y = fmaf(pv, v.y, acc4.y);                                                              \
    acc4.z = fmaf(pv, v.z, acc4.z);                                                              \
    acc4.w = fmaf(pv, v.w, acc4.w);                                                              \
  }
  PV_GATHER(0, 0) PV_GATHER(1, 0) PV_GATHER(2, 0) PV_GATHER(3, 0)
  PV_GATHER(4, 1) PV_GATHER(5, 1) PV_GATHER(6, 1) PV_GATHER(7, 1)
  PV_GATHER(8, 2) PV_GATHER(9, 2) PV_GATHER(10, 2) PV_GATHER(11, 2)
  if (tail) {  // p==0 masks beyond nn; m dummy 0 rows are L1-hot
    PV_GATHER(12, 3) PV_GATHER(13, 3) PV_GATHER(14, 3) PV_GATHER(15, 3)
    PV_GATHER(16, 4) PV_GATHER(17, 4) PV_GATHER(18, 4) PV_GATHER(19, 4)
  }
#undef PV_GATHER
  // reduce across the 4 row-groups (xor 16, 32); result replicated in all groups
  acc4.x += __shfl_xor(acc4.x, 16, 64);
  acc4.y += __shfl_xor(acc4.y, 16, 64);
  acc4.z += __shfl_xor(acc4.z, 16, 64);
  acc4.w += __shfl_xor(acc4.w, 16, 64);
  acc4.x += __shfl_xor(acc4.x, 32, 64);
  acc4.y += __shfl_xor(acc4.y, 32, 64);
  acc4.z += __shfl_xor(acc4.z, 32, 64);
  acc4.w += __shfl_xor(acc4.w, 32, 64);
  acc4.x *= inv;
  acc4.y *= inv;
  acc4.z *= inv;
  acc4.w *= inv;

  float4 sk4 = *(const float4*)(Sk + (size_t)wid * HD + e4);
  if (ELU1) {
    float vx = (acc4.x > 0.f ? acc4.x : (__expf(acc4.x) - 1.f)) + sk4.x;
    float vy = (acc4.y > 0.f ? acc4.y : (__expf(acc4.y) - 1.f)) + sk4.y;
    float vz = (acc4.z > 0.f ? acc4.z : (__expf(acc4.z) - 1.f)) + sk4.z;
    float vw = (acc4.w > 0.f ? acc4.w : (__expf(acc4.w) - 1.f)) + sk4.w;
    if (lane < 16) *(float4*)(xout + (size_t)wid * HD + e4) = make_float4(vx, vy, vz, vw);
  } else {
    float4 ro = *(const float4*)(roW + e4);
    float ws = (acc4.x + sk4.x) * ro.x + (acc4.y + sk4.y) * ro.y +
               (acc4.z + sk4.z) * ro.z + (acc4.w + sk4.w) * ro.w;
    ws += __shfl_xor(ws, 1, 64);
    ws += __shfl_xor(ws, 2, 64);
    ws += __shfl_xor(ws, 4, 64);
    ws += __shfl_xor(ws, 8, 64);
    if (lane == 0) out[wid] = ws + rob[0];
  }
}

extern "C" void kernel_launch(void* const* d_in, const int* in_sizes, int n_in,
                              void* d_out, int out_size, void* d_ws, size_t ws_size,
                              hipStream_t stream) {
  const float* stim = (const float*)d_in[0];
  const float* adj  = (const float*)d_in[1];
  const float* W1   = (const float*)d_in[2];
  const float* b1   = (const float*)d_in[3];
  const float* lng  = (const float*)d_in[4];
  const float* lnb  = (const float*)d_in[5];
  const float* W2   = (const float*)d_in[6];
  const float* b2   = (const float*)d_in[7];
  const float* emb  = (const float*)d_in[8];
  const float* Wg1  = (const float*)d_in[9];
  const float* Wg2  = (const float*)d_in[10];
  const float* s1w  = (const float*)d_in[11];
  const float* s1b  = (const float*)d_in[12];
  const float* s2w  = (const float*)d_in[13];
  const float* s2b  = (const float*)d_in[14];
  const float* roW  = (const float*)d_in[15];
  const float* rob  = (const float*)d_in[16];
  float* out = (float*)d_out;

  char* ws = (char*)d_ws;
  float* g    = (float*)(ws + 0);          // 256 f32
  float* part = (float*)(ws + 4096);       // 96 KB
  int*   cnt  = (int*)(ws + 131072);       // 4096 ints
  int*   cols = (int*)(ws + 147456);       // 4096*80 ints = 1.25 MB
  float* Wh   = (float*)(ws + 1572864);    // 4 MB  fp32 (PV)
  float* Sk   = (float*)(ws + 5767168);    // 4 MB
  float* x1   = (float*)(ws + 9961472);    // 4 MB
  u16*   Whh  = (u16*)(ws + 14155776);     // 2 MB  f16 (score gathers)

  enc_a_kernel<<<dim3(24, 4), dim3(256), 0, stream>>>(stim, W1, part);
  enc_b_kernel<<<dim3(4), dim3(128), 0, stream>>>(part, b1, lng, lnb, W2, b2, g);
  csr_kernel<<<dim3(NV), dim3(256), 0, stream>>>(adj, cnt, cols);
  whsk_kernel<1><<<dim3(NB * NV / 32), dim3(256), 0, stream>>>(g, emb, (const float*)nullptr,
                                                               Wg1, s1w, s1b, Wh, Whh, Sk);
  attn_kernel<true><<<dim3(NB * NV / 4), dim3(256), 0, stream>>>(Wh, Whh, Sk, cnt, cols, x1,
                                                                 roW, rob, (float*)nullptr);
  whsk_kernel<2><<<dim3(NB * NV / 32), dim3(256), 0, stream>>>(g, emb, x1, Wg2, s2w, s2b,
                                                               Wh, Whh, Sk);
  attn_kernel<false><<<dim3(NB * NV / 4), dim3(256), 0, stream>>>(Wh, Whh, Sk, cnt, cols,
                                                                  (float*)nullptr, roW, rob, out);
}

// Round 16
// 74.901 us; speedup vs baseline: 1.3529x; 1.1152x over previous
//
#include <hip/hip_runtime.h>
#include <math.h>

#define NB 4
#define NV 4096
#define DIN 3072
#define HD 64
#define CAP 80

typedef unsigned short u16;
typedef unsigned int u32;
typedef _Float16 h2 __attribute__((ext_vector_type(2)));

__device__ __forceinline__ float fdot2u(u32 v, u32 q, float c) {
#if __has_builtin(__builtin_amdgcn_fdot2)
  return __builtin_amdgcn_fdot2(__builtin_bit_cast(h2, v), __builtin_bit_cast(h2, q), c, false);
#else
  h2 a = __builtin_bit_cast(h2, v), b = __builtin_bit_cast(h2, q);
  return c + (float)a[0] * (float)b[0] + (float)a[1] * (float)b[1];
#endif
}

// packed f16 add of shfl_xor'd partner
__device__ __forceinline__ h2 sxh(h2 v, int off) {
  return v + __builtin_bit_cast(h2, (u32)__shfl_xor((int)__builtin_bit_cast(u32, v), off, 64));
}

// ---------------- encoder stage A: partial GEMV h_partial = stim @ W1 over k-chunks
__global__ __launch_bounds__(256) void enc_a_kernel(const float* __restrict__ stim,
                                                    const float* __restrict__ W1,
                                                    float* __restrict__ part) {
  int c = blockIdx.x;           // 24 k-chunks of 128
  int b = blockIdx.y;           // 4 batches
  int t = threadIdx.x;
  int j = t & 127, h = t >> 7;  // h: which 64-k half
  int k0 = c * 128 + h * 64;
  float acc = 0.f;
#pragma unroll 8
  for (int k = 0; k < 64; ++k)
    acc += stim[b * DIN + k0 + k] * W1[(size_t)(k0 + k) * 128 + j];
  part[((b * 24 + c) * 2 + h) * 128 + j] = acc;
}

// ---------------- encoder stage B: fixed-order reduce + LN + GELU + Linear(128->64)
__global__ __launch_bounds__(128) void enc_b_kernel(
    const float* __restrict__ part, const float* __restrict__ b1,
    const float* __restrict__ lng, const float* __restrict__ lnb,
    const float* __restrict__ W2, const float* __restrict__ b2, float* __restrict__ g) {
  int b = blockIdx.x;
  int t = threadIdx.x;
  float hv = 0.f;
  for (int c = 0; c < 48; ++c) hv += part[(b * 48 + c) * 128 + t];  // deterministic order
  hv += b1[t];
  __shared__ float act[128];
  __shared__ float red[128];
  __shared__ float s_mu, s_var;
  act[t] = hv;
  red[t] = hv;
  __syncthreads();
  for (int s = 64; s > 0; s >>= 1) {
    if (t < s) red[t] += red[t + s];
    __syncthreads();
  }
  if (t == 0) s_mu = red[0] * (1.f / 128.f);
  __syncthreads();
  float dv = act[t] - s_mu;
  red[t] = dv * dv;
  __syncthreads();
  for (int s = 64; s > 0; s >>= 1) {
    if (t < s) red[t] += red[t + s];
    __syncthreads();
  }
  if (t == 0) s_var = red[0] * (1.f / 128.f);
  __syncthreads();
  float y = (act[t] - s_mu) * rsqrtf(s_var + 1e-5f) * lng[t] + lnb[t];
  act[t] = 0.5f * y * (1.f + erff(y * 0.70710678118f));  // exact GELU
  __syncthreads();
  if (t < 64) {
    float a2 = 0.f;
    for (int k = 0; k < 128; ++k) a2 += act[k] * W2[k * 64 + t];
    g[b * 64 + t] = a2 + b2[t];
  }
}

// ---------------- deterministic neighbor-list build; shuffle prefix-scan; zero-filled tail
__global__ __launch_bounds__(256) void csr_kernel(const float* __restrict__ adj,
                                                  int* __restrict__ cnt, int* __restrict__ cols) {
  int row = blockIdx.x;
  int t = threadIdx.x;
  int l = t & 63, w = t >> 6;
  __shared__ int wtot[4];
  __shared__ int stot;
  const float4* p = (const float4*)(adj + (size_t)row * NV);
  float4 v0 = p[t], v1 = p[t + 256], v2 = p[t + 512], v3 = p[t + 768];
  int c = (v0.x > 0.f) + (v0.y > 0.f) + (v0.z > 0.f) + (v0.w > 0.f) +
          (v1.x > 0.f) + (v1.y > 0.f) + (v1.z > 0.f) + (v1.w > 0.f) +
          (v2.x > 0.f) + (v2.y > 0.f) + (v2.z > 0.f) + (v2.w > 0.f) +
          (v3.x > 0.f) + (v3.y > 0.f) + (v3.z > 0.f) + (v3.w > 0.f);
  int val = c;  // inclusive prefix within wave
#pragma unroll
  for (int off = 1; off < 64; off <<= 1) {
    int tmp = __shfl_up(val, off, 64);
    if (l >= off) val += tmp;
  }
  if (l == 63) wtot[w] = val;
  __syncthreads();
  int base = 0;
  for (int i = 0; i < w; ++i) base += wtot[i];
  if (t == 255) {
    int s = base + val;
    s = s > CAP ? CAP : s;
    cnt[row] = s;
    stot = s;
  }
  int o = base + (val - c);  // exclusive global prefix
  int* cr = cols + row * CAP;
#define EMIT(vv, jj) if ((vv) > 0.f) { if (o < CAP) cr[o] = (jj); ++o; }
  int j0 = t * 4, j1 = (t + 256) * 4, j2 = (t + 512) * 4, j3 = (t + 768) * 4;
  EMIT(v0.x, j0) EMIT(v0.y, j0 + 1) EMIT(v0.z, j0 + 2) EMIT(v0.w, j0 + 3)
  EMIT(v1.x, j1) EMIT(v1.y, j1 + 1) EMIT(v1.z, j1 + 2) EMIT(v1.w, j1 + 3)
  EMIT(v2.x, j2) EMIT(v2.y, j2 + 1) EMIT(v2.z, j2 + 2) EMIT(v2.w, j2 + 3)
  EMIT(v3.x, j3) EMIT(v3.y, j3 + 1) EMIT(v3.z, j3 + 2) EMIT(v3.w, j3 + 3)
#undef EMIT
  __syncthreads();
  if (t < CAP && t >= stot) cr[t] = 0;  // valid row id; p==0 masks it in attn
}

// ---------------- fused Whh(f16) = x@Wg and Sk = x@Sw + sb   (fp32 Wh no longer needed)
template <int LAYER>
__global__ __launch_bounds__(256) void whsk_kernel(
    const float* __restrict__ g, const float* __restrict__ emb, const float* __restrict__ xin,
    const float* __restrict__ Wg, const float* __restrict__ Sw, const float* __restrict__ Sb,
    u16* __restrict__ Whh, float* __restrict__ Sk) {
  __shared__ float wg[4096];
  __shared__ float sw[4096];
  __shared__ float xs[2048];
  __shared__ float sbs[64];
  int tid = threadIdx.x;
  for (int i = tid; i < 4096; i += 256) {
    wg[i] = Wg[i];
    sw[i] = Sw[i];
  }
  if (tid < 64) sbs[tid] = Sb[tid];
  int base = blockIdx.x * 32;  // 32 rows per block; all same batch
  int b = base >> 12;
  for (int i = tid; i < 2048; i += 256) {
    int rr = i >> 6, k = i & 63;
    int grow = base + rr;
    if (LAYER == 1) {
      int n = grow & (NV - 1);
      xs[i] = g[b * 64 + k] + emb[(size_t)n * 64 + k];
    } else {
      xs[i] = xin[(size_t)grow * 64 + k];
    }
  }
  __syncthreads();
  int cidx = tid & 63, r0 = tid >> 6;
  for (int rr = r0; rr < 32; rr += 4) {
    float aw = 0.f, as = 0.f;
#pragma unroll
    for (int k = 0; k < 64; ++k) {
      float xv = xs[rr * 64 + k];
      aw += xv * wg[k * 64 + cidx];
      as += xv * sw[k * 64 + cidx];
    }
    int grow = base + rr;
    _Float16 hv = (_Float16)aw;  // RNE f32->f16
    Whh[(size_t)grow * 64 + cidx] = __builtin_bit_cast(u16, hv);
    Sk[(size_t)grow * 64 + cidx] = as + sbs[cidx];
  }
}

// ---------------- sparse GAT attention: wave/row; XCD-pinned; f16 fdot2 scores;
// PV reuses score-phase registers (zero PV loads for nn<=48): packed-f16 FMA + 4-step
// packed shuffle-tree over the 16 same-q lanes. Tail (nn>48) reloads its rows (L2-hot).
template <bool ELU1>
__global__ __launch_bounds__(256) void attn_kernel(
    const u16* __restrict__ Whh, const float* __restrict__ Sk,
    const int* __restrict__ cnt, const int* __restrict__ cols, float* __restrict__ xout,
    const float* __restrict__ roW, const float* __restrict__ rob, float* __restrict__ out) {
  int tid = threadIdx.x;
  int lane = tid & 63;
  int w = tid >> 6;
  int bid = blockIdx.x;
  int x = bid & 7;       // XCD slot
  int gidx = bid >> 3;   // 0..511
  int b = x >> 1;        // batch pinned to XCD pair
  int n = __builtin_amdgcn_readfirstlane((x & 1) * 2048 + gidx * 4 + w);
  int wid = b * NV + n;
  const u16* whhbase = Whh + (size_t)b * (NV * HD);
  int nn = __builtin_amdgcn_readfirstlane(cnt[n]);
  const int* cl = cols + n * CAP;
  int q = lane & 3;    // lane-in-quad: owns f16 elems [8q,8q+8) and [32+8q,+8)
  int gq = lane >> 2;  // quad 0..15: owns neighbor slot gq of each 16-block

  // f16 query: packed half2 words
  const uint4* qr = (const uint4*)(whhbase + (size_t)n * HD);
  uint4 QA = qr[q];
  uint4 QB = qr[q + 4];

  float s[5], p[5];
  uint4 SA0, SB0, SA1, SB1, SA2, SB2;
#define SCORE_BLOCK(jb, SAv, SBv)                                                                \
  {                                                                                              \
    int j = (jb) * 16 + gq;                                                                      \
    int m = cl[j];                                                                               \
    const uint4* vr = (const uint4*)(whhbase + (size_t)m * HD);                                  \
    SAv = vr[q];                                                                                 \
    SBv = vr[q + 4];                                                                             \
    float t = 0.f;                                                                               \
    t = fdot2u(SAv.x, QA.x, t);                                                                  \
    t = fdot2u(SAv.y, QA.y, t);                                                                  \
    t = fdot2u(SAv.z, QA.z, t);                                                                  \
    t = fdot2u(SAv.w, QA.w, t);                                                                  \
    t = fdot2u(SBv.x, QB.x, t);                                                                  \
    t = fdot2u(SBv.y, QB.y, t);                                                                  \
    t = fdot2u(SBv.z, QB.z, t);                                                                  \
    t = fdot2u(SBv.w, QB.w, t);                                                                  \
    t += __shfl_xor(t, 1, 64);                                                                   \
    t += __shfl_xor(t, 2, 64);                                                                   \
    s[jb] = (j < nn) ? t * 0.125f : -1e30f;                                                      \
  }

  SCORE_BLOCK(0, SA0, SB0)
  SCORE_BLOCK(1, SA1, SB1)
  SCORE_BLOCK(2, SA2, SB2)
  s[3] = -1e30f;
  s[4] = -1e30f;
  bool tail = (nn > 48);  // wave-uniform
  if (tail) {
    uint4 TA, TB;
    SCORE_BLOCK(3, TA, TB)
    SCORE_BLOCK(4, TA, TB)
  }
#undef SCORE_BLOCK

  // softmax: 4-step quad-class reduces; each j counted once -> inv = 1/sum
  float mx = fmaxf(fmaxf(fmaxf(s[0], s[1]), fmaxf(s[2], s[3])), s[4]);
  mx = fmaxf(mx, __shfl_xor(mx, 4, 64));
  mx = fmaxf(mx, __shfl_xor(mx, 8, 64));
  mx = fmaxf(mx, __shfl_xor(mx, 16, 64));
  mx = fmaxf(mx, __shfl_xor(mx, 32, 64));
  float sum = 0.f;
#pragma unroll
  for (int jb = 0; jb < 5; ++jb) {
    p[jb] = (jb * 16 + gq < nn) ? __expf(s[jb] - mx) : 0.f;
    sum += p[jb];
  }
  sum += __shfl_xor(sum, 4, 64);
  sum += __shfl_xor(sum, 8, 64);
  sum += __shfl_xor(sum, 16, 64);
  sum += __shfl_xor(sum, 32, 64);
  float inv = 1.f / sum;

  // PV: packed-f16 FMA on register-resident rows. aa[k]: k<4 -> elems 8q+2k..+1;
  // k>=4 -> elems 32+8q+2(k-4)..+1.
  h2 aa[8];
#pragma unroll
  for (int k = 0; k < 8; ++k) aa[k] = h2{(_Float16)0, (_Float16)0};
#define PV_ACC(pp, Av, Bv)                                                                       \
  {                                                                                              \
    _Float16 pf = (_Float16)(pp);                                                                \
    h2 ph = {pf, pf};                                                                            \
    aa[0] += __builtin_bit_cast(h2, (Av).x) * ph;                                                \
    aa[1] += __builtin_bit_cast(h2, (Av).y) * ph;                                                \
    aa[2] += __builtin_bit_cast(h2, (Av).z) * ph;                                                \
    aa[3] += __builtin_bit_cast(h2, (Av).w) * ph;                                                \
    aa[4] += __builtin_bit_cast(h2, (Bv).x) * ph;                                                \
    aa[5] += __builtin_bit_cast(h2, (Bv).y) * ph;                                                \
    aa[6] += __builtin_bit_cast(h2, (Bv).z) * ph;                                                \
    aa[7] += __builtin_bit_cast(h2, (Bv).w) * ph;                                                \
  }
  PV_ACC(p[0], SA0, SB0)
  PV_ACC(p[1], SA1, SB1)
  PV_ACC(p[2], SA2, SB2)
  if (tail) {  // reload tail rows (L2-hot); p==0 masks beyond nn
    int m3 = cl[48 + gq];
    const uint4* vr3 = (const uint4*)(whhbase + (size_t)m3 * HD);
    uint4 A3 = vr3[q], B3 = vr3[q + 4];
    PV_ACC(p[3], A3, B3)
    if (nn > 64) {
      int m4 = cl[64 + gq];
      const uint4* vr4 = (const uint4*)(whhbase + (size_t)m4 * HD);
      uint4 A4 = vr4[q], B4 = vr4[q + 4];
      PV_ACC(p[4], A4, B4)
    }
  }
#undef PV_ACC

  // reduce over the 16 same-q lanes (packed adds); result replicated across gq
#pragma unroll
  for (int k = 0; k < 8; ++k) {
    aa[k] = sxh(aa[k], 4);
    aa[k] = sxh(aa[k], 8);
    aa[k] = sxh(aa[k], 16);
    aa[k] = sxh(aa[k], 32);
  }
  float f[16];
#pragma unroll
  for (int k = 0; k < 8; ++k) {
    f[2 * k] = (float)aa[k][0];
    f[2 * k + 1] = (float)aa[k][1];
  }

  size_t obase = (size_t)wid * HD;
  if (ELU1) {
    if (gq == 0) {  // lanes 0-3 cover all 64 elems
      float4 skA = *(const float4*)(Sk + obase + 8 * q);
      float4 skB = *(const float4*)(Sk + obase + 8 * q + 4);
      float4 skC = *(const float4*)(Sk + obase + 32 + 8 * q);
      float4 skD = *(const float4*)(Sk + obase + 32 + 8 * q + 4);
#define ELU(v) ((v) > 0.f ? (v) : (__expf(v) - 1.f))
      float4 oA = make_float4(ELU(f[0] * inv) + skA.x, ELU(f[1] * inv) + skA.y,
                              ELU(f[2] * inv) + skA.z, ELU(f[3] * inv) + skA.w);
      float4 oB = make_float4(ELU(f[4] * inv) + skB.x, ELU(f[5] * inv) + skB.y,
                              ELU(f[6] * inv) + skB.z, ELU(f[7] * inv) + skB.w);
      float4 oC = make_float4(ELU(f[8] * inv) + skC.x, ELU(f[9] * inv) + skC.y,
                              ELU(f[10] * inv) + skC.z, ELU(f[11] * inv) + skC.w);
      float4 oD = make_float4(ELU(f[12] * inv) + skD.x, ELU(f[13] * inv) + skD.y,
                              ELU(f[14] * inv) + skD.z, ELU(f[15] * inv) + skD.w);
#undef ELU
      *(float4*)(xout + obase + 8 * q) = oA;
      *(float4*)(xout + obase + 8 * q + 4) = oB;
      *(float4*)(xout + obase + 32 + 8 * q) = oC;
      *(float4*)(xout + obase + 32 + 8 * q + 4) = oD;
    }
  } else {
    float4 skA = *(const float4*)(Sk + obase + 8 * q);
    float4 skB = *(const float4*)(Sk + obase + 8 * q + 4);
    float4 skC = *(const float4*)(Sk + obase + 32 + 8 * q);
    float4 skD = *(const float4*)(Sk + obase + 32 + 8 * q + 4);
    float4 roA = *(const float4*)(roW + 8 * q);
    float4 roB = *(const float4*)(roW + 8 * q + 4);
    float4 roC = *(const float4*)(roW + 32 + 8 * q);
    float4 roD = *(const float4*)(roW + 32 + 8 * q + 4);
    float ws = (f[0] * inv + skA.x) * roA.x + (f[1] * inv + skA.y) * roA.y +
               (f[2] * inv + skA.z) * roA.z + (f[3] * inv + skA.w) * roA.w +
               (f[4] * inv + skB.x) * roB.x + (f[5] * inv + skB.y) * roB.y +
               (f[6] * inv + skB.z) * roB.z + (f[7] * inv + skB.w) * roB.w +
               (f[8] * inv + skC.x) * roC.x + (f[9] * inv + skC.y) * roC.y +
               (f[10] * inv + skC.z) * roC.z + (f[11] * inv + skC.w) * roC.w +
               (f[12] * inv + skD.x) * roD.x + (f[13] * inv + skD.y) * roD.y +
               (f[14] * inv + skD.z) * roD.z + (f[15] * inv + skD.w) * roD.w;
    ws += __shfl_xor(ws, 1, 64);  // sum over q within quad
    ws += __shfl_xor(ws, 2, 64);
    if (lane == 0) out[wid] = ws + rob[0];
  }
}

extern "C" void kernel_launch(void* const* d_in, const int* in_sizes, int n_in,
                              void* d_out, int out_size, void* d_ws, size_t ws_size,
                              hipStream_t stream) {
  const float* stim = (const float*)d_in[0];
  const float* adj  = (const float*)d_in[1];
  const float* W1   = (const float*)d_in[2];
  const float* b1   = (const float*)d_in[3];
  const float* lng  = (const float*)d_in[4];
  const float* lnb  = (const float*)d_in[5];
  const float* W2   = (const float*)d_in[6];
  const float* b2   = (const float*)d_in[7];
  const float* emb  = (const float*)d_in[8];
  const float* Wg1  = (const float*)d_in[9];
  const float* Wg2  = (const float*)d_in[10];
  const float* s1w  = (const float*)d_in[11];
  const float* s1b  = (const float*)d_in[12];
  const float* s2w  = (const float*)d_in[13];
  const float* s2b  = (const float*)d_in[14];
  const float* roW  = (const float*)d_in[15];
  const float* rob  = (const float*)d_in[16];
  float* out = (float*)d_out;

  char* ws = (char*)d_ws;
  float* g    = (float*)(ws + 0);          // 256 f32
  float* part = (float*)(ws + 4096);       // 96 KB
  int*   cnt  = (int*)(ws + 131072);       // 4096 ints
  int*   cols = (int*)(ws + 147456);       // 4096*80 ints = 1.25 MB
  float* Sk   = (float*)(ws + 5767168);    // 4 MB
  float* x1   = (float*)(ws + 9961472);    // 4 MB
  u16*   Whh  = (u16*)(ws + 14155776);     // 2 MB  f16 rows (scores + PV)

  enc_a_kernel<<<dim3(24, 4), dim3(256), 0, stream>>>(stim, W1, part);
  enc_b_kernel<<<dim3(4), dim3(128), 0, stream>>>(part, b1, lng, lnb, W2, b2, g);
  csr_kernel<<<dim3(NV), dim3(256), 0, stream>>>(adj, cnt, cols);
  whsk_kernel<1><<<dim3(NB * NV / 32), dim3(256), 0, stream>>>(g, emb, (const float*)nullptr,
                                                               Wg1, s1w, s1b, Whh, Sk);
  attn_kernel<true><<<dim3(NB * NV / 4), dim3(256), 0, stream>>>(Whh, Sk, cnt, cols, x1,
                                                                 roW, rob, (float*)nullptr);
  whsk_kernel<2><<<dim3(NB * NV / 32), dim3(256), 0, stream>>>(g, emb, x1, Wg2, s2w, s2b,
                                                               Whh, Sk);
  attn_kernel<false><<<dim3(NB * NV / 4), dim3(256), 0, stream>>>(Whh, Sk, cnt, cols,
                                                                  (float*)nullptr, roW, rob, out);
}

// Round 17
// 67.574 us; speedup vs baseline: 1.4996x; 1.1084x over previous
//
#include <hip/hip_runtime.h>
#include <math.h>

#define NB 4
#define NV 4096
#define DIN 3072
#define HD 64
#define CAP 80

typedef unsigned short u16;
typedef unsigned int u32;
typedef _Float16 h2 __attribute__((ext_vector_type(2)));

__device__ __forceinline__ float fdot2u(u32 v, u32 q, float c) {
#if __has_builtin(__builtin_amdgcn_fdot2)
  return __builtin_amdgcn_fdot2(__builtin_bit_cast(h2, v), __builtin_bit_cast(h2, q), c, false);
#else
  h2 a = __builtin_bit_cast(h2, v), b = __builtin_bit_cast(h2, q);
  return c + (float)a[0] * (float)b[0] + (float)a[1] * (float)b[1];
#endif
}

// packed f16 add of shfl_xor'd partner
__device__ __forceinline__ h2 sxh(h2 v, int off) {
  return v + __builtin_bit_cast(h2, (u32)__shfl_xor((int)__builtin_bit_cast(u32, v), off, 64));
}

// ---------------- fused: csr build (blocks 0..4095) || encoder stage A (blocks 4096..4191)
__global__ __launch_bounds__(256) void pre_kernel(
    const float* __restrict__ adj, int* __restrict__ cnt, int* __restrict__ cols,
    const float* __restrict__ stim, const float* __restrict__ W1, float* __restrict__ part) {
  int bid = blockIdx.x;
  int t = threadIdx.x;
  if (bid < NV) {
    // ---- csr: deterministic neighbor-list; shuffle prefix-scan; zero-filled tail
    int row = bid;
    int l = t & 63, w = t >> 6;
    __shared__ int wtot[4];
    __shared__ int stot;
    const float4* p = (const float4*)(adj + (size_t)row * NV);
    float4 v0 = p[t], v1 = p[t + 256], v2 = p[t + 512], v3 = p[t + 768];
    int c = (v0.x > 0.f) + (v0.y > 0.f) + (v0.z > 0.f) + (v0.w > 0.f) +
            (v1.x > 0.f) + (v1.y > 0.f) + (v1.z > 0.f) + (v1.w > 0.f) +
            (v2.x > 0.f) + (v2.y > 0.f) + (v2.z > 0.f) + (v2.w > 0.f) +
            (v3.x > 0.f) + (v3.y > 0.f) + (v3.z > 0.f) + (v3.w > 0.f);
    int val = c;  // inclusive prefix within wave
#pragma unroll
    for (int off = 1; off < 64; off <<= 1) {
      int tmp = __shfl_up(val, off, 64);
      if (l >= off) val += tmp;
    }
    if (l == 63) wtot[w] = val;
    __syncthreads();
    int base = 0;
    for (int i = 0; i < w; ++i) base += wtot[i];
    if (t == 255) {
      int s = base + val;
      s = s > CAP ? CAP : s;
      cnt[row] = s;
      stot = s;
    }
    int o = base + (val - c);  // exclusive global prefix
    int* cr = cols + row * CAP;
#define EMIT(vv, jj) if ((vv) > 0.f) { if (o < CAP) cr[o] = (jj); ++o; }
    int j0 = t * 4, j1 = (t + 256) * 4, j2 = (t + 512) * 4, j3 = (t + 768) * 4;
    EMIT(v0.x, j0) EMIT(v0.y, j0 + 1) EMIT(v0.z, j0 + 2) EMIT(v0.w, j0 + 3)
    EMIT(v1.x, j1) EMIT(v1.y, j1 + 1) EMIT(v1.z, j1 + 2) EMIT(v1.w, j1 + 3)
    EMIT(v2.x, j2) EMIT(v2.y, j2 + 1) EMIT(v2.z, j2 + 2) EMIT(v2.w, j2 + 3)
    EMIT(v3.x, j3) EMIT(v3.y, j3 + 1) EMIT(v3.z, j3 + 2) EMIT(v3.w, j3 + 3)
#undef EMIT
    __syncthreads();
    if (t < CAP && t >= stot) cr[t] = 0;  // valid row id; p==0 masks it in attn
  } else {
    // ---- enc_a: partial GEMV over k-chunks
    int e = bid - NV;
    int c = e % 24;  // k-chunk
    int b = e / 24;  // batch
    int j = t & 127, h = t >> 7;
    int k0 = c * 128 + h * 64;
    float acc = 0.f;
#pragma unroll 8
    for (int k = 0; k < 64; ++k)
      acc += stim[b * DIN + k0 + k] * W1[(size_t)(k0 + k) * 128 + j];
    part[((b * 24 + c) * 2 + h) * 128 + j] = acc;
  }
}

// ---------------- encoder stage B: fixed-order reduce + LN + GELU + Linear(128->64)
__global__ __launch_bounds__(128) void enc_b_kernel(
    const float* __restrict__ part, const float* __restrict__ b1,
    const float* __restrict__ lng, const float* __restrict__ lnb,
    const float* __restrict__ W2, const float* __restrict__ b2, float* __restrict__ g) {
  int b = blockIdx.x;
  int t = threadIdx.x;
  float hv = 0.f;
  for (int c = 0; c < 48; ++c) hv += part[(b * 48 + c) * 128 + t];  // deterministic order
  hv += b1[t];
  __shared__ float act[128];
  __shared__ float red[128];
  __shared__ float s_mu, s_var;
  act[t] = hv;
  red[t] = hv;
  __syncthreads();
  for (int s = 64; s > 0; s >>= 1) {
    if (t < s) red[t] += red[t + s];
    __syncthreads();
  }
  if (t == 0) s_mu = red[0] * (1.f / 128.f);
  __syncthreads();
  float dv = act[t] - s_mu;
  red[t] = dv * dv;
  __syncthreads();
  for (int s = 64; s > 0; s >>= 1) {
    if (t < s) red[t] += red[t + s];
    __syncthreads();
  }
  if (t == 0) s_var = red[0] * (1.f / 128.f);
  __syncthreads();
  float y = (act[t] - s_mu) * rsqrtf(s_var + 1e-5f) * lng[t] + lnb[t];
  act[t] = 0.5f * y * (1.f + erff(y * 0.70710678118f));  // exact GELU
  __syncthreads();
  if (t < 64) {
    float a2 = 0.f;
    for (int k = 0; k < 128; ++k) a2 += act[k] * W2[k * 64 + t];
    g[b * 64 + t] = a2 + b2[t];
  }
}

// ---------------- fused Whh(f16) = x@Wg and Sk = x@Sw + sb
// Each thread: 4 consecutive output cols (cg) x 2 rows (r0, r0+16).
// Weights natural [k][c] LDS, float4 reads (2-way alias = free).
// x staged transposed xst[k*33+rr] -> per-k scalar reads hit 16 distinct banks.
template <int LAYER>
__global__ __launch_bounds__(256) void whsk_kernel(
    const float* __restrict__ g, const float* __restrict__ emb, const float* __restrict__ xin,
    const float* __restrict__ Wg, const float* __restrict__ Sw, const float* __restrict__ Sb,
    u16* __restrict__ Whh, float* __restrict__ Sk) {
  __shared__ float wgt[4096];
  __shared__ float swt[4096];
  __shared__ float xst[64 * 33];
  __shared__ float sbs[64];
  int tid = threadIdx.x;
  for (int i = tid; i < 1024; i += 256) {
    ((float4*)wgt)[i] = ((const float4*)Wg)[i];
    ((float4*)swt)[i] = ((const float4*)Sw)[i];
  }
  if (tid < 64) sbs[tid] = Sb[tid];
  int base = blockIdx.x * 32;  // 32 rows per block; all same batch
  int b = base >> 12;
  for (int i4 = tid; i4 < 512; i4 += 256) {
    int rr = i4 >> 4, k0 = (i4 & 15) * 4;
    int grow = base + rr;
    float4 v;
    if (LAYER == 1) {
      int n = grow & (NV - 1);
      float4 gv = *(const float4*)(g + b * 64 + k0);
      float4 ev = *(const float4*)(emb + (size_t)n * 64 + k0);
      v = make_float4(gv.x + ev.x, gv.y + ev.y, gv.z + ev.z, gv.w + ev.w);
    } else {
      v = *(const float4*)(xin + (size_t)grow * 64 + k0);
    }
    xst[(k0 + 0) * 33 + rr] = v.x;
    xst[(k0 + 1) * 33 + rr] = v.y;
    xst[(k0 + 2) * 33 + rr] = v.z;
    xst[(k0 + 3) * 33 + rr] = v.w;
  }
  __syncthreads();
  int cg = tid & 15;   // cols 4cg..4cg+3
  int r0 = tid >> 4;   // rows r0 and r0+16
  float4 aw0 = make_float4(0, 0, 0, 0), as0 = make_float4(0, 0, 0, 0);
  float4 aw1 = make_float4(0, 0, 0, 0), as1 = make_float4(0, 0, 0, 0);
#pragma unroll 4
  for (int k = 0; k < 64; ++k) {
    float4 wv = *(const float4*)&wgt[k * 64 + 4 * cg];
    float4 sv = *(const float4*)&swt[k * 64 + 4 * cg];
    float x0 = xst[k * 33 + r0];
    float x1 = xst[k * 33 + r0 + 16];
    aw0.x = fmaf(x0, wv.x, aw0.x); aw0.y = fmaf(x0, wv.y, aw0.y);
    aw0.z = fmaf(x0, wv.z, aw0.z); aw0.w = fmaf(x0, wv.w, aw0.w);
    as0.x = fmaf(x0, sv.x, as0.x); as0.y = fmaf(x0, sv.y, as0.y);
    as0.z = fmaf(x0, sv.z, as0.z); as0.w = fmaf(x0, sv.w, as0.w);
    aw1.x = fmaf(x1, wv.x, aw1.x); aw1.y = fmaf(x1, wv.y, aw1.y);
    aw1.z = fmaf(x1, wv.z, aw1.z); aw1.w = fmaf(x1, wv.w, aw1.w);
    as1.x = fmaf(x1, sv.x, as1.x); as1.y = fmaf(x1, sv.y, as1.y);
    as1.z = fmaf(x1, sv.z, as1.z); as1.w = fmaf(x1, sv.w, as1.w);
  }
  float4 sb4 = *(const float4*)&sbs[4 * cg];
  int grow0 = base + r0, grow1 = base + r0 + 16;
  ushort4 h0, h1;
  h0.x = __builtin_bit_cast(u16, (_Float16)aw0.x);
  h0.y = __builtin_bit_cast(u16, (_Float16)aw0.y);
  h0.z = __builtin_bit_cast(u16, (_Float16)aw0.z);
  h0.w = __builtin_bit_cast(u16, (_Float16)aw0.w);
  h1.x = __builtin_bit_cast(u16, (_Float16)aw1.x);
  h1.y = __builtin_bit_cast(u16, (_Float16)aw1.y);
  h1.z = __builtin_bit_cast(u16, (_Float16)aw1.z);
  h1.w = __builtin_bit_cast(u16, (_Float16)aw1.w);
  *(ushort4*)(Whh + (size_t)grow0 * 64 + 4 * cg) = h0;
  *(ushort4*)(Whh + (size_t)grow1 * 64 + 4 * cg) = h1;
  *(float4*)(Sk + (size_t)grow0 * 64 + 4 * cg) =
      make_float4(as0.x + sb4.x, as0.y + sb4.y, as0.z + sb4.z, as0.w + sb4.w);
  *(float4*)(Sk + (size_t)grow1 * 64 + 4 * cg) =
      make_float4(as1.x + sb4.x, as1.y + sb4.y, as1.z + sb4.z, as1.w + sb4.w);
}

// ---------------- sparse GAT attention (unchanged from r16 winner): wave/row; XCD-pinned;
// f16 fdot2 scores; PV reuses score-phase registers; packed shuffle-tree reduce.
template <bool ELU1>
__global__ __launch_bounds__(256) void attn_kernel(
    const u16* __restrict__ Whh, const float* __restrict__ Sk,
    const int* __restrict__ cnt, const int* __restrict__ cols, float* __restrict__ xout,
    const float* __restrict__ roW, const float* __restrict__ rob, float* __restrict__ out) {
  int tid = threadIdx.x;
  int lane = tid & 63;
  int w = tid >> 6;
  int bid = blockIdx.x;
  int x = bid & 7;       // XCD slot
  int gidx = bid >> 3;   // 0..511
  int b = x >> 1;        // batch pinned to XCD pair
  int n = __builtin_amdgcn_readfirstlane((x & 1) * 2048 + gidx * 4 + w);
  int wid = b * NV + n;
  const u16* whhbase = Whh + (size_t)b * (NV * HD);
  int nn = __builtin_amdgcn_readfirstlane(cnt[n]);
  const int* cl = cols + n * CAP;
  int q = lane & 3;    // lane-in-quad: owns f16 elems [8q,8q+8) and [32+8q,+8)
  int gq = lane >> 2;  // quad 0..15: owns neighbor slot gq of each 16-block

  const uint4* qr = (const uint4*)(whhbase + (size_t)n * HD);
  uint4 QA = qr[q];
  uint4 QB = qr[q + 4];

  float s[5], p[5];
  uint4 SA0, SB0, SA1, SB1, SA2, SB2;
#define SCORE_BLOCK(jb, SAv, SBv)                                                                \
  {                                                                                              \
    int j = (jb) * 16 + gq;                                                                      \
    int m = cl[j];                                                                               \
    const uint4* vr = (const uint4*)(whhbase + (size_t)m * HD);                                  \
    SAv = vr[q];                                                                                 \
    SBv = vr[q + 4];                                                                             \
    float t = 0.f;                                                                               \
    t = fdot2u(SAv.x, QA.x, t);                                                                  \
    t = fdot2u(SAv.y, QA.y, t);                                                                  \
    t = fdot2u(SAv.z, QA.z, t);                                                                  \
    t = fdot2u(SAv.w, QA.w, t);                                                                  \
    t = fdot2u(SBv.x, QB.x, t);                                                                  \
    t = fdot2u(SBv.y, QB.y, t);                                                                  \
    t = fdot2u(SBv.z, QB.z, t);                                                                  \
    t = fdot2u(SBv.w, QB.w, t);                                                                  \
    t += __shfl_xor(t, 1, 64);                                                                   \
    t += __shfl_xor(t, 2, 64);                                                                   \
    s[jb] = (j < nn) ? t * 0.125f : -1e30f;                                                      \
  }

  SCORE_BLOCK(0, SA0, SB0)
  SCORE_BLOCK(1, SA1, SB1)
  SCORE_BLOCK(2, SA2, SB2)
  s[3] = -1e30f;
  s[4] = -1e30f;
  bool tail = (nn > 48);  // wave-uniform
  if (tail) {
    uint4 TA, TB;
    SCORE_BLOCK(3, TA, TB)
    SCORE_BLOCK(4, TA, TB)
  }
#undef SCORE_BLOCK

  float mx = fmaxf(fmaxf(fmaxf(s[0], s[1]), fmaxf(s[2], s[3])), s[4]);
  mx = fmaxf(mx, __shfl_xor(mx, 4, 64));
  mx = fmaxf(mx, __shfl_xor(mx, 8, 64));
  mx = fmaxf(mx, __shfl_xor(mx, 16, 64));
  mx = fmaxf(mx, __shfl_xor(mx, 32, 64));
  float sum = 0.f;
#pragma unroll
  for (int jb = 0; jb < 5; ++jb) {
    p[jb] = (jb * 16 + gq < nn) ? __expf(s[jb] - mx) : 0.f;
    sum += p[jb];
  }
  sum += __shfl_xor(sum, 4, 64);
  sum += __shfl_xor(sum, 8, 64);
  sum += __shfl_xor(sum, 16, 64);
  sum += __shfl_xor(sum, 32, 64);
  float inv = 1.f / sum;

  h2 aa[8];
#pragma unroll
  for (int k = 0; k < 8; ++k) aa[k] = h2{(_Float16)0, (_Float16)0};
#define PV_ACC(pp, Av, Bv)                                                                       \
  {                                                                                              \
    _Float16 pf = (_Float16)(pp);                                                                \
    h2 ph = {pf, pf};                                                                            \
    aa[0] += __builtin_bit_cast(h2, (Av).x) * ph;                                                \
    aa[1] += __builtin_bit_cast(h2, (Av).y) * ph;                                                \
    aa[2] += __builtin_bit_cast(h2, (Av).z) * ph;                                                \
    aa[3] += __builtin_bit_cast(h2, (Av).w) * ph;                                                \
    aa[4] += __builtin_bit_cast(h2, (Bv).x) * ph;                                                \
    aa[5] += __builtin_bit_cast(h2, (Bv).y) * ph;                                                \
    aa[6] += __builtin_bit_cast(h2, (Bv).z) * ph;                                                \
    aa[7] += __builtin_bit_cast(h2, (Bv).w) * ph;                                                \
  }
  PV_ACC(p[0], SA0, SB0)
  PV_ACC(p[1], SA1, SB1)
  PV_ACC(p[2], SA2, SB2)
  if (tail) {  // reload tail rows (L2-hot); p==0 masks beyond nn
    int m3 = cl[48 + gq];
    const uint4* vr3 = (const uint4*)(whhbase + (size_t)m3 * HD);
    uint4 A3 = vr3[q], B3 = vr3[q + 4];
    PV_ACC(p[3], A3, B3)
    if (nn > 64) {
      int m4 = cl[64 + gq];
      const uint4* vr4 = (const uint4*)(whhbase + (size_t)m4 * HD);
      uint4 A4 = vr4[q], B4 = vr4[q + 4];
      PV_ACC(p[4], A4, B4)
    }
  }
#undef PV_ACC

#pragma unroll
  for (int k = 0; k < 8; ++k) {
    aa[k] = sxh(aa[k], 4);
    aa[k] = sxh(aa[k], 8);
    aa[k] = sxh(aa[k], 16);
    aa[k] = sxh(aa[k], 32);
  }
  float f[16];
#pragma unroll
  for (int k = 0; k < 8; ++k) {
    f[2 * k] = (float)aa[k][0];
    f[2 * k + 1] = (float)aa[k][1];
  }

  size_t obase = (size_t)wid * HD;
  if (ELU1) {
    if (gq == 0) {  // lanes 0-3 cover all 64 elems
      float4 skA = *(const float4*)(Sk + obase + 8 * q);
      float4 skB = *(const float4*)(Sk + obase + 8 * q + 4);
      float4 skC = *(const float4*)(Sk + obase + 32 + 8 * q);
      float4 skD = *(const float4*)(Sk + obase + 32 + 8 * q + 4);
#define ELU(v) ((v) > 0.f ? (v) : (__expf(v) - 1.f))
      float4 oA = make_float4(ELU(f[0] * inv) + skA.x, ELU(f[1] * inv) + skA.y,
                              ELU(f[2] * inv) + skA.z, ELU(f[3] * inv) + skA.w);
      float4 oB = make_float4(ELU(f[4] * inv) + skB.x, ELU(f[5] * inv) + skB.y,
                              ELU(f[6] * inv) + skB.z, ELU(f[7] * inv) + skB.w);
      float4 oC = make_float4(ELU(f[8] * inv) + skC.x, ELU(f[9] * inv) + skC.y,
                              ELU(f[10] * inv) + skC.z, ELU(f[11] * inv) + skC.w);
      float4 oD = make_float4(ELU(f[12] * inv) + skD.x, ELU(f[13] * inv) + skD.y,
                              ELU(f[14] * inv) + skD.z, ELU(f[15] * inv) + skD.w);
#undef ELU
      *(float4*)(xout + obase + 8 * q) = oA;
      *(float4*)(xout + obase + 8 * q + 4) = oB;
      *(float4*)(xout + obase + 32 + 8 * q) = oC;
      *(float4*)(xout + obase + 32 + 8 * q + 4) = oD;
    }
  } else {
    float4 skA = *(const float4*)(Sk + obase + 8 * q);
    float4 skB = *(const float4*)(Sk + obase + 8 * q + 4);
    float4 skC = *(const float4*)(Sk + obase + 32 + 8 * q);
    float4 skD = *(const float4*)(Sk + obase + 32 + 8 * q + 4);
    float4 roA = *(const float4*)(roW + 8 * q);
    float4 roB = *(const float4*)(roW + 8 * q + 4);
    float4 roC = *(const float4*)(roW + 32 + 8 * q);
    float4 roD = *(const float4*)(roW + 32 + 8 * q + 4);
    float ws = (f[0] * inv + skA.x) * roA.x + (f[1] * inv + skA.y) * roA.y +
               (f[2] * inv + skA.z) * roA.z + (f[3] * inv + skA.w) * roA.w +
               (f[4] * inv + skB.x) * roB.x + (f[5] * inv + skB.y) * roB.y +
               (f[6] * inv + skB.z) * roB.z + (f[7] * inv + skB.w) * roB.w +
               (f[8] * inv + skC.x) * roC.x + (f[9] * inv + skC.y) * roC.y +
               (f[10] * inv + skC.z) * roC.z + (f[11] * inv + skC.w) * roC.w +
               (f[12] * inv + skD.x) * roD.x + (f[13] * inv + skD.y) * roD.y +
               (f[14] * inv + skD.z) * roD.z + (f[15] * inv + skD.w) * roD.w;
    ws += __shfl_xor(ws, 1, 64);  // sum over q within quad
    ws += __shfl_xor(ws, 2, 64);
    if (lane == 0) out[wid] = ws + rob[0];
  }
}

extern "C" void kernel_launch(void* const* d_in, const int* in_sizes, int n_in,
                              void* d_out, int out_size, void* d_ws, size_t ws_size,
                              hipStream_t stream) {
  const float* stim = (const float*)d_in[0];
  const float* adj  = (const float*)d_in[1];
  const float* W1   = (const float*)d_in[2];
  const float* b1   = (const float*)d_in[3];
  const float* lng  = (const float*)d_in[4];
  const float* lnb  = (const float*)d_in[5];
  const float* W2   = (const float*)d_in[6];
  const float* b2   = (const float*)d_in[7];
  const float* emb  = (const float*)d_in[8];
  const float* Wg1  = (const float*)d_in[9];
  const float* Wg2  = (const float*)d_in[10];
  const float* s1w  = (const float*)d_in[11];
  const float* s1b  = (const float*)d_in[12];
  const float* s2w  = (const float*)d_in[13];
  const float* s2b  = (const float*)d_in[14];
  const float* roW  = (const float*)d_in[15];
  const float* rob  = (const float*)d_in[16];
  float* out = (float*)d_out;

  char* ws = (char*)d_ws;
  float* g    = (float*)(ws + 0);          // 256 f32
  float* part = (float*)(ws + 4096);       // 96 KB
  int*   cnt  = (int*)(ws + 131072);       // 4096 ints
  int*   cols = (int*)(ws + 147456);       // 4096*80 ints = 1.25 MB
  float* Sk   = (float*)(ws + 5767168);    // 4 MB
  float* x1   = (float*)(ws + 9961472);    // 4 MB
  u16*   Whh  = (u16*)(ws + 14155776);     // 2 MB  f16 rows (scores + PV)

  pre_kernel<<<dim3(NV + 96), dim3(256), 0, stream>>>(adj, cnt, cols, stim, W1, part);
  enc_b_kernel<<<dim3(4), dim3(128), 0, stream>>>(part, b1, lng, lnb, W2, b2, g);
  whsk_kernel<1><<<dim3(NB * NV / 32), dim3(256), 0, stream>>>(g, emb, (const float*)nullptr,
                                                               Wg1, s1w, s1b, Whh, Sk);
  attn_kernel<true><<<dim3(NB * NV / 4), dim3(256), 0, stream>>>(Whh, Sk, cnt, cols, x1,
                                                                 roW, rob, (float*)nullptr);
  whsk_kernel<2><<<dim3(NB * NV / 32), dim3(256), 0, stream>>>(g, emb, x1, Wg2, s2w, s2b,
                                                               Whh, Sk);
  attn_kernel<false><<<dim3(NB * NV / 4), dim3(256), 0, stream>>>(Whh, Sk, cnt, cols,
                                                                  (float*)nullptr, roW, rob, out);
}

// Round 18
// 62.779 us; speedup vs baseline: 1.6141x; 1.0764x over previous
//
#include <hip/hip_runtime.h>
#include <math.h>

#define NB 4
#define NV 4096
#define DIN 3072
#define HD 64
#define CAP 80

typedef unsigned short u16;
typedef unsigned int u32;
typedef _Float16 h2 __attribute__((ext_vector_type(2)));

__device__ __forceinline__ float fdot2u(u32 v, u32 q, float c) {
#if __has_builtin(__builtin_amdgcn_fdot2)
  return __builtin_amdgcn_fdot2(__builtin_bit_cast(h2, v), __builtin_bit_cast(h2, q), c, false);
#else
  h2 a = __builtin_bit_cast(h2, v), b = __builtin_bit_cast(h2, q);
  return c + (float)a[0] * (float)b[0] + (float)a[1] * (float)b[1];
#endif
}

// raw shuffled packed value
__device__ __forceinline__ h2 shx(h2 v, int off) {
  return __builtin_bit_cast(h2, (u32)__shfl_xor((int)__builtin_bit_cast(u32, v), off, 64));
}

// ---------------- fused: csr build (blocks 0..4095) || encoder stage A (blocks 4096..4191)
__global__ __launch_bounds__(256) void pre_kernel(
    const float* __restrict__ adj, int* __restrict__ cnt, int* __restrict__ cols,
    const float* __restrict__ stim, const float* __restrict__ W1, float* __restrict__ part) {
  int bid = blockIdx.x;
  int t = threadIdx.x;
  if (bid < NV) {
    int row = bid;
    int l = t & 63, w = t >> 6;
    __shared__ int wtot[4];
    __shared__ int stot;
    const float4* p = (const float4*)(adj + (size_t)row * NV);
    float4 v0 = p[t], v1 = p[t + 256], v2 = p[t + 512], v3 = p[t + 768];
    int c = (v0.x > 0.f) + (v0.y > 0.f) + (v0.z > 0.f) + (v0.w > 0.f) +
            (v1.x > 0.f) + (v1.y > 0.f) + (v1.z > 0.f) + (v1.w > 0.f) +
            (v2.x > 0.f) + (v2.y > 0.f) + (v2.z > 0.f) + (v2.w > 0.f) +
            (v3.x > 0.f) + (v3.y > 0.f) + (v3.z > 0.f) + (v3.w > 0.f);
    int val = c;  // inclusive prefix within wave
#pragma unroll
    for (int off = 1; off < 64; off <<= 1) {
      int tmp = __shfl_up(val, off, 64);
      if (l >= off) val += tmp;
    }
    if (l == 63) wtot[w] = val;
    __syncthreads();
    int base = 0;
    for (int i = 0; i < w; ++i) base += wtot[i];
    if (t == 255) {
      int s = base + val;
      s = s > CAP ? CAP : s;
      cnt[row] = s;
      stot = s;
    }
    int o = base + (val - c);  // exclusive global prefix
    int* cr = cols + row * CAP;
#define EMIT(vv, jj) if ((vv) > 0.f) { if (o < CAP) cr[o] = (jj); ++o; }
    int j0 = t * 4, j1 = (t + 256) * 4, j2 = (t + 512) * 4, j3 = (t + 768) * 4;
    EMIT(v0.x, j0) EMIT(v0.y, j0 + 1) EMIT(v0.z, j0 + 2) EMIT(v0.w, j0 + 3)
    EMIT(v1.x, j1) EMIT(v1.y, j1 + 1) EMIT(v1.z, j1 + 2) EMIT(v1.w, j1 + 3)
    EMIT(v2.x, j2) EMIT(v2.y, j2 + 1) EMIT(v2.z, j2 + 2) EMIT(v2.w, j2 + 3)
    EMIT(v3.x, j3) EMIT(v3.y, j3 + 1) EMIT(v3.z, j3 + 2) EMIT(v3.w, j3 + 3)
#undef EMIT
    __syncthreads();
    if (t < CAP && t >= stot) cr[t] = 0;  // valid row id; p==0 masks it in attn
  } else {
    int e = bid - NV;
    int c = e % 24;  // k-chunk
    int b = e / 24;  // batch
    int j = t & 127, h = t >> 7;
    int k0 = c * 128 + h * 64;
    float acc = 0.f;
#pragma unroll 8
    for (int k = 0; k < 64; ++k)
      acc += stim[b * DIN + k0 + k] * W1[(size_t)(k0 + k) * 128 + j];
    part[((b * 24 + c) * 2 + h) * 128 + j] = acc;
  }
}

// ---------------- encoder stage B: fixed-order reduce + LN + GELU + Linear(128->64)
__global__ __launch_bounds__(128) void enc_b_kernel(
    const float* __restrict__ part, const float* __restrict__ b1,
    const float* __restrict__ lng, const float* __restrict__ lnb,
    const float* __restrict__ W2, const float* __restrict__ b2, float* __restrict__ g) {
  int b = blockIdx.x;
  int t = threadIdx.x;
  float hv = 0.f;
  for (int c = 0; c < 48; ++c) hv += part[(b * 48 + c) * 128 + t];  // deterministic order
  hv += b1[t];
  __shared__ float act[128];
  __shared__ float red[128];
  __shared__ float s_mu, s_var;
  act[t] = hv;
  red[t] = hv;
  __syncthreads();
  for (int s = 64; s > 0; s >>= 1) {
    if (t < s) red[t] += red[t + s];
    __syncthreads();
  }
  if (t == 0) s_mu = red[0] * (1.f / 128.f);
  __syncthreads();
  float dv = act[t] - s_mu;
  red[t] = dv * dv;
  __syncthreads();
  for (int s = 64; s > 0; s >>= 1) {
    if (t < s) red[t] += red[t + s];
    __syncthreads();
  }
  if (t == 0) s_var = red[0] * (1.f / 128.f);
  __syncthreads();
  float y = (act[t] - s_mu) * rsqrtf(s_var + 1e-5f) * lng[t] + lnb[t];
  act[t] = 0.5f * y * (1.f + erff(y * 0.70710678118f));  // exact GELU
  __syncthreads();
  if (t < 64) {
    float a2 = 0.f;
    for (int k = 0; k < 128; ++k) a2 += act[k] * W2[k * 64 + t];
    g[b * 64 + t] = a2 + b2[t];
  }
}

// ---------------- fused Whh(f16) = x@Wg and Sk = x@Sw + sb  (r17 structure)
template <int LAYER>
__global__ __launch_bounds__(256) void whsk_kernel(
    const float* __restrict__ g, const float* __restrict__ emb, const float* __restrict__ xin,
    const float* __restrict__ Wg, const float* __restrict__ Sw, const float* __restrict__ Sb,
    u16* __restrict__ Whh, float* __restrict__ Sk) {
  __shared__ float wgt[4096];
  __shared__ float swt[4096];
  __shared__ float xst[64 * 33];
  __shared__ float sbs[64];
  int tid = threadIdx.x;
  for (int i = tid; i < 1024; i += 256) {
    ((float4*)wgt)[i] = ((const float4*)Wg)[i];
    ((float4*)swt)[i] = ((const float4*)Sw)[i];
  }
  if (tid < 64) sbs[tid] = Sb[tid];
  int base = blockIdx.x * 32;  // 32 rows per block; all same batch
  int b = base >> 12;
  for (int i4 = tid; i4 < 512; i4 += 256) {
    int rr = i4 >> 4, k0 = (i4 & 15) * 4;
    int grow = base + rr;
    float4 v;
    if (LAYER == 1) {
      int n = grow & (NV - 1);
      float4 gv = *(const float4*)(g + b * 64 + k0);
      float4 ev = *(const float4*)(emb + (size_t)n * 64 + k0);
      v = make_float4(gv.x + ev.x, gv.y + ev.y, gv.z + ev.z, gv.w + ev.w);
    } else {
      v = *(const float4*)(xin + (size_t)grow * 64 + k0);
    }
    xst[(k0 + 0) * 33 + rr] = v.x;
    xst[(k0 + 1) * 33 + rr] = v.y;
    xst[(k0 + 2) * 33 + rr] = v.z;
    xst[(k0 + 3) * 33 + rr] = v.w;
  }
  __syncthreads();
  int cg = tid & 15;   // cols 4cg..4cg+3
  int r0 = tid >> 4;   // rows r0 and r0+16
  float4 aw0 = make_float4(0, 0, 0, 0), as0 = make_float4(0, 0, 0, 0);
  float4 aw1 = make_float4(0, 0, 0, 0), as1 = make_float4(0, 0, 0, 0);
#pragma unroll 4
  for (int k = 0; k < 64; ++k) {
    float4 wv = *(const float4*)&wgt[k * 64 + 4 * cg];
    float4 sv = *(const float4*)&swt[k * 64 + 4 * cg];
    float x0 = xst[k * 33 + r0];
    float x1 = xst[k * 33 + r0 + 16];
    aw0.x = fmaf(x0, wv.x, aw0.x); aw0.y = fmaf(x0, wv.y, aw0.y);
    aw0.z = fmaf(x0, wv.z, aw0.z); aw0.w = fmaf(x0, wv.w, aw0.w);
    as0.x = fmaf(x0, sv.x, as0.x); as0.y = fmaf(x0, sv.y, as0.y);
    as0.z = fmaf(x0, sv.z, as0.z); as0.w = fmaf(x0, sv.w, as0.w);
    aw1.x = fmaf(x1, wv.x, aw1.x); aw1.y = fmaf(x1, wv.y, aw1.y);
    aw1.z = fmaf(x1, wv.z, aw1.z); aw1.w = fmaf(x1, wv.w, aw1.w);
    as1.x = fmaf(x1, sv.x, as1.x); as1.y = fmaf(x1, sv.y, as1.y);
    as1.z = fmaf(x1, sv.z, as1.z); as1.w = fmaf(x1, sv.w, as1.w);
  }
  float4 sb4 = *(const float4*)&sbs[4 * cg];
  int grow0 = base + r0, grow1 = base + r0 + 16;
  ushort4 h0, h1;
  h0.x = __builtin_bit_cast(u16, (_Float16)aw0.x);
  h0.y = __builtin_bit_cast(u16, (_Float16)aw0.y);
  h0.z = __builtin_bit_cast(u16, (_Float16)aw0.z);
  h0.w = __builtin_bit_cast(u16, (_Float16)aw0.w);
  h1.x = __builtin_bit_cast(u16, (_Float16)aw1.x);
  h1.y = __builtin_bit_cast(u16, (_Float16)aw1.y);
  h1.z = __builtin_bit_cast(u16, (_Float16)aw1.z);
  h1.w = __builtin_bit_cast(u16, (_Float16)aw1.w);
  *(ushort4*)(Whh + (size_t)grow0 * 64 + 4 * cg) = h0;
  *(ushort4*)(Whh + (size_t)grow1 * 64 + 4 * cg) = h1;
  *(float4*)(Sk + (size_t)grow0 * 64 + 4 * cg) =
      make_float4(as0.x + sb4.x, as0.y + sb4.y, as0.z + sb4.z, as0.w + sb4.w);
  *(float4*)(Sk + (size_t)grow1 * 64 + 4 * cg) =
      make_float4(as1.x + sb4.x, as1.y + sb4.y, as1.z + sb4.z, as1.w + sb4.w);
}

// ---------------- sparse GAT attention: wave/row; XCD-pinned; f16 fdot2 scores;
// PV on register-resident rows; reduce-SCATTER tree (8 shuffles vs 32); lean epilogue.
template <bool ELU1>
__global__ __launch_bounds__(256) void attn_kernel(
    const u16* __restrict__ Whh, const float* __restrict__ Sk,
    const int* __restrict__ cnt, const int* __restrict__ cols, float* __restrict__ xout,
    const float* __restrict__ roW, const float* __restrict__ rob, float* __restrict__ out) {
  int tid = threadIdx.x;
  int lane = tid & 63;
  int w = tid >> 6;
  int bid = blockIdx.x;
  int x = bid & 7;       // XCD slot
  int gidx = bid >> 3;   // 0..511
  int b = x >> 1;        // batch pinned to XCD pair
  int n = __builtin_amdgcn_readfirstlane((x & 1) * 2048 + gidx * 4 + w);
  int wid = b * NV + n;
  const u16* whhbase = Whh + (size_t)b * (NV * HD);
  int nn = __builtin_amdgcn_readfirstlane(cnt[n]);
  const int* cl = cols + n * CAP;
  int q = lane & 3;    // lane-in-quad: owns f16 elems [8q,8q+8) and [32+8q,+8)
  int gq = lane >> 2;  // quad 0..15: owns neighbor slot gq of each 16-block

  const uint4* qr = (const uint4*)(whhbase + (size_t)n * HD);
  uint4 QA = qr[q];
  uint4 QB = qr[q + 4];

  float s[5], p[5];
  uint4 SA0, SB0, SA1, SB1, SA2, SB2;
#define SCORE_BLOCK(jb, SAv, SBv)                                                                \
  {                                                                                              \
    int j = (jb) * 16 + gq;                                                                      \
    int m = cl[j];                                                                               \
    const uint4* vr = (const uint4*)(whhbase + (size_t)m * HD);                                  \
    SAv = vr[q];                                                                                 \
    SBv = vr[q + 4];                                                                             \
    float t = 0.f;                                                                               \
    t = fdot2u(SAv.x, QA.x, t);                                                                  \
    t = fdot2u(SAv.y, QA.y, t);                                                                  \
    t = fdot2u(SAv.z, QA.z, t);                                                                  \
    t = fdot2u(SAv.w, QA.w, t);                                                                  \
    t = fdot2u(SBv.x, QB.x, t);                                                                  \
    t = fdot2u(SBv.y, QB.y, t);                                                                  \
    t = fdot2u(SBv.z, QB.z, t);                                                                  \
    t = fdot2u(SBv.w, QB.w, t);                                                                  \
    t += __shfl_xor(t, 1, 64);                                                                   \
    t += __shfl_xor(t, 2, 64);                                                                   \
    s[jb] = (j < nn) ? t * 0.125f : -1e30f;                                                      \
  }

  SCORE_BLOCK(0, SA0, SB0)
  SCORE_BLOCK(1, SA1, SB1)
  SCORE_BLOCK(2, SA2, SB2)
  s[3] = -1e30f;
  s[4] = -1e30f;
  bool tail = (nn > 48);  // wave-uniform
  if (tail) {
    uint4 TA, TB;
    SCORE_BLOCK(3, TA, TB)
    SCORE_BLOCK(4, TA, TB)
  }
#undef SCORE_BLOCK

  float mx = fmaxf(fmaxf(fmaxf(s[0], s[1]), fmaxf(s[2], s[3])), s[4]);
  mx = fmaxf(mx, __shfl_xor(mx, 4, 64));
  mx = fmaxf(mx, __shfl_xor(mx, 8, 64));
  mx = fmaxf(mx, __shfl_xor(mx, 16, 64));
  mx = fmaxf(mx, __shfl_xor(mx, 32, 64));
  float sum = 0.f;
#pragma unroll
  for (int jb = 0; jb < 5; ++jb) {
    p[jb] = (jb * 16 + gq < nn) ? __expf(s[jb] - mx) : 0.f;
    sum += p[jb];
  }
  sum += __shfl_xor(sum, 4, 64);
  sum += __shfl_xor(sum, 8, 64);
  sum += __shfl_xor(sum, 16, 64);
  sum += __shfl_xor(sum, 32, 64);
  float inv = 1.f / sum;

  // PV: packed-f16 FMA on register-resident rows. aa[k]: k<4 -> elems [8q+2k,+1];
  // k>=4 -> [32+8q+2(k-4),+1].
  h2 aa[8];
#pragma unroll
  for (int k = 0; k < 8; ++k) aa[k] = h2{(_Float16)0, (_Float16)0};
#define PV_ACC(pp, Av, Bv)                                                                       \
  {                                                                                              \
    _Float16 pf = (_Float16)(pp);                                                                \
    h2 ph = {pf, pf};                                                                            \
    aa[0] += __builtin_bit_cast(h2, (Av).x) * ph;                                                \
    aa[1] += __builtin_bit_cast(h2, (Av).y) * ph;                                                \
    aa[2] += __builtin_bit_cast(h2, (Av).z) * ph;                                                \
    aa[3] += __builtin_bit_cast(h2, (Av).w) * ph;                                                \
    aa[4] += __builtin_bit_cast(h2, (Bv).x) * ph;                                                \
    aa[5] += __builtin_bit_cast(h2, (Bv).y) * ph;                                                \
    aa[6] += __builtin_bit_cast(h2, (Bv).z) * ph;                                                \
    aa[7] += __builtin_bit_cast(h2, (Bv).w) * ph;                                                \
  }
  PV_ACC(p[0], SA0, SB0)
  PV_ACC(p[1], SA1, SB1)
  PV_ACC(p[2], SA2, SB2)
  if (tail) {  // reload tail rows (L2-hot); p==0 masks beyond nn
    int m3 = cl[48 + gq];
    const uint4* vr3 = (const uint4*)(whhbase + (size_t)m3 * HD);
    uint4 A3 = vr3[q], B3 = vr3[q + 4];
    PV_ACC(p[3], A3, B3)
    if (nn > 64) {
      int m4 = cl[64 + gq];
      const uint4* vr4 = (const uint4*)(whhbase + (size_t)m4 * HD);
      uint4 A4 = vr4[q], B4 = vr4[q + 4];
      PV_ACC(p[4], A4, B4)
    }
  }
#undef PV_ACC

  // reduce-SCATTER over gq bits (partner keeps half, gives half): 4+2+1+1 = 8 shuffles.
  // Lane ends with elem pair a = 8q + 32*(gq&1) + 4*((gq>>1)&1) + 2*((gq>>2)&1),
  // duplicated across gq&8.
  bool g1 = (gq & 1) != 0;
  h2 bb[4];
#pragma unroll
  for (int i = 0; i < 4; ++i) {
    h2 k = g1 ? aa[i + 4] : aa[i];
    h2 u = g1 ? aa[i] : aa[i + 4];
    bb[i] = k + shx(u, 4);
  }
  bool g2 = (gq & 2) != 0;
  h2 cc[2];
#pragma unroll
  for (int i = 0; i < 2; ++i) {
    h2 k = g2 ? bb[i + 2] : bb[i];
    h2 u = g2 ? bb[i] : bb[i + 2];
    cc[i] = k + shx(u, 8);
  }
  bool g4 = (gq & 4) != 0;
  h2 dd;
  {
    h2 k = g4 ? cc[1] : cc[0];
    h2 u = g4 ? cc[0] : cc[1];
    dd = k + shx(u, 16);
  }
  dd = dd + shx(dd, 32);
  int a = 8 * q + 32 * (gq & 1) + 4 * ((gq >> 1) & 1) + 2 * ((gq >> 2) & 1);
  float f0 = (float)dd[0] * inv;
  float f1 = (float)dd[1] * inv;

  size_t obase = (size_t)wid * HD;
  float2 sk2 = *(const float2*)(Sk + obase + a);
  if (ELU1) {
    float o0 = (f0 > 0.f ? f0 : (__expf(f0) - 1.f)) + sk2.x;
    float o1 = (f1 > 0.f ? f1 : (__expf(f1) - 1.f)) + sk2.y;
    if ((gq & 8) == 0) *(float2*)(xout + obase + a) = make_float2(o0, o1);
  } else {
    float2 ro2 = *(const float2*)(roW + a);
    float wsp = (f0 + sk2.x) * ro2.x + (f1 + sk2.y) * ro2.y;
    // lanes 0..31 cover all 32 elem-pairs once; reduce within each 32-half
    wsp += __shfl_xor(wsp, 1, 64);
    wsp += __shfl_xor(wsp, 2, 64);
    wsp += __shfl_xor(wsp, 4, 64);
    wsp += __shfl_xor(wsp, 8, 64);
    wsp += __shfl_xor(wsp, 16, 64);
    if (lane == 0) out[wid] = wsp + rob[0];
  }
}

extern "C" void kernel_launch(void* const* d_in, const int* in_sizes, int n_in,
                              void* d_out, int out_size, void* d_ws, size_t ws_size,
                              hipStream_t stream) {
  const float* stim = (const float*)d_in[0];
  const float* adj  = (const float*)d_in[1];
  const float* W1   = (const float*)d_in[2];
  const float* b1   = (const float*)d_in[3];
  const float* lng  = (const float*)d_in[4];
  const float* lnb  = (const float*)d_in[5];
  const float* W2   = (const float*)d_in[6];
  const float* b2   = (const float*)d_in[7];
  const float* emb  = (const float*)d_in[8];
  const float* Wg1  = (const float*)d_in[9];
  const float* Wg2  = (const float*)d_in[10];
  const float* s1w  = (const float*)d_in[11];
  const float* s1b  = (const float*)d_in[12];
  const float* s2w  = (const float*)d_in[13];
  const float* s2b  = (const float*)d_in[14];
  const float* roW  = (const float*)d_in[15];
  const float* rob  = (const float*)d_in[16];
  float* out = (float*)d_out;

  char* ws = (char*)d_ws;
  float* g    = (float*)(ws + 0);          // 256 f32
  float* part = (float*)(ws + 4096);       // 96 KB
  int*   cnt  = (int*)(ws + 131072);       // 4096 ints
  int*   cols = (int*)(ws + 147456);       // 4096*80 ints = 1.25 MB
  float* Sk   = (float*)(ws + 5767168);    // 4 MB
  float* x1   = (float*)(ws + 9961472);    // 4 MB
  u16*   Whh  = (u16*)(ws + 14155776);     // 2 MB  f16 rows (scores + PV)

  pre_kernel<<<dim3(NV + 96), dim3(256), 0, stream>>>(adj, cnt, cols, stim, W1, part);
  enc_b_kernel<<<dim3(4), dim3(128), 0, stream>>>(part, b1, lng, lnb, W2, b2, g);
  whsk_kernel<1><<<dim3(NB * NV / 32), dim3(256), 0, stream>>>(g, emb, (const float*)nullptr,
                                                               Wg1, s1w, s1b, Whh, Sk);
  attn_kernel<true><<<dim3(NB * NV / 4), dim3(256), 0, stream>>>(Whh, Sk, cnt, cols, x1,
                                                                 roW, rob, (float*)nullptr);
  whsk_kernel<2><<<dim3(NB * NV / 32), dim3(256), 0, stream>>>(g, emb, x1, Wg2, s2w, s2b,
                                                               Whh, Sk);
  attn_kernel<false><<<dim3(NB * NV / 4), dim3(256), 0, stream>>>(Whh, Sk, cnt, cols,
                                                                  (float*)nullptr, roW, rob, out);
}

// Round 19
// 61.130 us; speedup vs baseline: 1.6577x; 1.0270x over previous
//
#include <hip/hip_runtime.h>
#include <math.h>

#define NB 4
#define NV 4096
#define DIN 3072
#define HD 64
#define CAP 80

typedef unsigned short u16;
typedef unsigned int u32;
typedef _Float16 h2 __attribute__((ext_vector_type(2)));

__device__ __forceinline__ float fdot2u(u32 v, u32 q, float c) {
#if __has_builtin(__builtin_amdgcn_fdot2)
  return __builtin_amdgcn_fdot2(__builtin_bit_cast(h2, v), __builtin_bit_cast(h2, q), c, false);
#else
  h2 a = __builtin_bit_cast(h2, v), b = __builtin_bit_cast(h2, q);
  return c + (float)a[0] * (float)b[0] + (float)a[1] * (float)b[1];
#endif
}

__device__ __forceinline__ h2 shx(h2 v, int off) {
  return __builtin_bit_cast(h2, (u32)__shfl_xor((int)__builtin_bit_cast(u32, v), off, 64));
}

// ---------------- fused: csr build (blocks 0..4095) || encoder stage A (blocks 4096..4191)
__global__ __launch_bounds__(256) void pre_kernel(
    const float* __restrict__ adj, int* __restrict__ cnt, int* __restrict__ cols,
    const float* __restrict__ stim, const float* __restrict__ W1, float* __restrict__ part) {
  int bid = blockIdx.x;
  int t = threadIdx.x;
  if (bid < NV) {
    int row = bid;
    int l = t & 63, w = t >> 6;
    __shared__ int wtot[4];
    __shared__ int stot;
    const float4* p = (const float4*)(adj + (size_t)row * NV);
    float4 v0 = p[t], v1 = p[t + 256], v2 = p[t + 512], v3 = p[t + 768];
    int c = (v0.x > 0.f) + (v0.y > 0.f) + (v0.z > 0.f) + (v0.w > 0.f) +
            (v1.x > 0.f) + (v1.y > 0.f) + (v1.z > 0.f) + (v1.w > 0.f) +
            (v2.x > 0.f) + (v2.y > 0.f) + (v2.z > 0.f) + (v2.w > 0.f) +
            (v3.x > 0.f) + (v3.y > 0.f) + (v3.z > 0.f) + (v3.w > 0.f);
    int val = c;  // inclusive prefix within wave
#pragma unroll
    for (int off = 1; off < 64; off <<= 1) {
      int tmp = __shfl_up(val, off, 64);
      if (l >= off) val += tmp;
    }
    if (l == 63) wtot[w] = val;
    __syncthreads();
    int base = 0;
    for (int i = 0; i < w; ++i) base += wtot[i];
    if (t == 255) {
      int s = base + val;
      s = s > CAP ? CAP : s;
      cnt[row] = s;
      stot = s;
    }
    int o = base + (val - c);  // exclusive global prefix
    int* cr = cols + row * CAP;
#define EMIT(vv, jj) if ((vv) > 0.f) { if (o < CAP) cr[o] = (jj); ++o; }
    int j0 = t * 4, j1 = (t + 256) * 4, j2 = (t + 512) * 4, j3 = (t + 768) * 4;
    EMIT(v0.x, j0) EMIT(v0.y, j0 + 1) EMIT(v0.z, j0 + 2) EMIT(v0.w, j0 + 3)
    EMIT(v1.x, j1) EMIT(v1.y, j1 + 1) EMIT(v1.z, j1 + 2) EMIT(v1.w, j1 + 3)
    EMIT(v2.x, j2) EMIT(v2.y, j2 + 1) EMIT(v2.z, j2 + 2) EMIT(v2.w, j2 + 3)
    EMIT(v3.x, j3) EMIT(v3.y, j3 + 1) EMIT(v3.z, j3 + 2) EMIT(v3.w, j3 + 3)
#undef EMIT
    __syncthreads();
    if (t < CAP && t >= stot) cr[t] = 0;  // valid row id; p==0 masks it in attn
  } else {
    int e = bid - NV;
    int c = e % 24;  // k-chunk
    int b = e / 24;  // batch
    int j = t & 127, h = t >> 7;
    int k0 = c * 128 + h * 64;
    float acc = 0.f;
#pragma unroll 8
    for (int k = 0; k < 64; ++k)
      acc += stim[b * DIN + k0 + k] * W1[(size_t)(k0 + k) * 128 + j];
    part[((b * 24 + c) * 2 + h) * 128 + j] = acc;
  }
}

// ---------------- whsk1 with enc_b recomputed per block (deterministic, identical per block)
__global__ __launch_bounds__(256) void whsk1_kernel(
    const float* __restrict__ part, const float* __restrict__ b1,
    const float* __restrict__ lng, const float* __restrict__ lnb,
    const float* __restrict__ W2, const float* __restrict__ b2,
    const float* __restrict__ emb, const float* __restrict__ Wg,
    const float* __restrict__ Sw, const float* __restrict__ Sb,
    u16* __restrict__ Whh, float* __restrict__ Sk) {
  __shared__ float wgt[4096];
  __shared__ float swt[4096];
  __shared__ float xst[64 * 33];
  __shared__ float sbs[64];
  __shared__ float act[128];
  __shared__ float red[128];
  __shared__ __align__(16) float gs[64];
  __shared__ float s_mu, s_var;
  int tid = threadIdx.x;
  int base = blockIdx.x * 32;  // 32 rows per block; all same batch
  int b = base >> 12;

  // weights -> LDS (independent of enc_b chain)
  for (int i = tid; i < 1024; i += 256) {
    ((float4*)wgt)[i] = ((const float4*)Wg)[i];
    ((float4*)swt)[i] = ((const float4*)Sw)[i];
  }
  if (tid < 64) sbs[tid] = Sb[tid];
  // enc_b: h = sum part + b1 (deterministic order)
  if (tid < 128) {
    float hv = 0.f;
    for (int c = 0; c < 48; ++c) hv += part[(b * 48 + c) * 128 + tid];
    hv += b1[tid];
    act[tid] = hv;
    red[tid] = hv;
  }
  __syncthreads();
  for (int s = 64; s > 0; s >>= 1) {
    if (tid < s) red[tid] += red[tid + s];
    __syncthreads();
  }
  if (tid == 0) s_mu = red[0] * (1.f / 128.f);
  __syncthreads();
  if (tid < 128) { float dv = act[tid] - s_mu; red[tid] = dv * dv; }
  __syncthreads();
  for (int s = 64; s > 0; s >>= 1) {
    if (tid < s) red[tid] += red[tid + s];
    __syncthreads();
  }
  if (tid == 0) s_var = red[0] * (1.f / 128.f);
  __syncthreads();
  if (tid < 128) {
    float y = (act[tid] - s_mu) * rsqrtf(s_var + 1e-5f) * lng[tid] + lnb[tid];
    act[tid] = 0.5f * y * (1.f + erff(y * 0.70710678118f));  // exact GELU
  }
  __syncthreads();
  if (tid < 64) {
    float a2 = 0.f;
    for (int k = 0; k < 128; ++k) a2 += act[k] * W2[k * 64 + tid];
    gs[tid] = a2 + b2[tid];
  }
  __syncthreads();
  // stage x = g + emb, transposed
  for (int i4 = tid; i4 < 512; i4 += 256) {
    int rr = i4 >> 4, k0 = (i4 & 15) * 4;
    int n = (base + rr) & (NV - 1);
    float4 gv = *(const float4*)(gs + k0);
    float4 ev = *(const float4*)(emb + (size_t)n * 64 + k0);
    xst[(k0 + 0) * 33 + rr] = gv.x + ev.x;
    xst[(k0 + 1) * 33 + rr] = gv.y + ev.y;
    xst[(k0 + 2) * 33 + rr] = gv.z + ev.z;
    xst[(k0 + 3) * 33 + rr] = gv.w + ev.w;
  }
  __syncthreads();
  int cg = tid & 15;  // cols 4cg..4cg+3
  int r0 = tid >> 4;  // rows r0 and r0+16
  float4 aw0 = make_float4(0, 0, 0, 0), as0 = make_float4(0, 0, 0, 0);
  float4 aw1 = make_float4(0, 0, 0, 0), as1 = make_float4(0, 0, 0, 0);
#pragma unroll 4
  for (int k = 0; k < 64; ++k) {
    float4 wv = *(const float4*)&wgt[k * 64 + 4 * cg];
    float4 sv = *(const float4*)&swt[k * 64 + 4 * cg];
    float x0 = xst[k * 33 + r0];
    float x1v = xst[k * 33 + r0 + 16];
    aw0.x = fmaf(x0, wv.x, aw0.x); aw0.y = fmaf(x0, wv.y, aw0.y);
    aw0.z = fmaf(x0, wv.z, aw0.z); aw0.w = fmaf(x0, wv.w, aw0.w);
    as0.x = fmaf(x0, sv.x, as0.x); as0.y = fmaf(x0, sv.y, as0.y);
    as0.z = fmaf(x0, sv.z, as0.z); as0.w = fmaf(x0, sv.w, as0.w);
    aw1.x = fmaf(x1v, wv.x, aw1.x); aw1.y = fmaf(x1v, wv.y, aw1.y);
    aw1.z = fmaf(x1v, wv.z, aw1.z); aw1.w = fmaf(x1v, wv.w, aw1.w);
    as1.x = fmaf(x1v, sv.x, as1.x); as1.y = fmaf(x1v, sv.y, as1.y);
    as1.z = fmaf(x1v, sv.z, as1.z); as1.w = fmaf(x1v, sv.w, as1.w);
  }
  float4 sb4 = *(const float4*)&sbs[4 * cg];
  int grow0 = base + r0, grow1 = base + r0 + 16;
  ushort4 h0, h1;
  h0.x = __builtin_bit_cast(u16, (_Float16)aw0.x);
  h0.y = __builtin_bit_cast(u16, (_Float16)aw0.y);
  h0.z = __builtin_bit_cast(u16, (_Float16)aw0.z);
  h0.w = __builtin_bit_cast(u16, (_Float16)aw0.w);
  h1.x = __builtin_bit_cast(u16, (_Float16)aw1.x);
  h1.y = __builtin_bit_cast(u16, (_Float16)aw1.y);
  h1.z = __builtin_bit_cast(u16, (_Float16)aw1.z);
  h1.w = __builtin_bit_cast(u16, (_Float16)aw1.w);
  *(ushort4*)(Whh + (size_t)grow0 * 64 + 4 * cg) = h0;
  *(ushort4*)(Whh + (size_t)grow1 * 64 + 4 * cg) = h1;
  *(float4*)(Sk + (size_t)grow0 * 64 + 4 * cg) =
      make_float4(as0.x + sb4.x, as0.y + sb4.y, as0.z + sb4.z, as0.w + sb4.w);
  *(float4*)(Sk + (size_t)grow1 * 64 + 4 * cg) =
      make_float4(as1.x + sb4.x, as1.y + sb4.y, as1.z + sb4.z, as1.w + sb4.w);
}

// ---------------- attn layer1 fused with whsk2: 8 waves = 8 rows; x1 stays in LDS;
// 2-wave whsk tail produces Whh2/Sk2. Attention math identical to r18.
__global__ __launch_bounds__(512) void attn_l1_kernel(
    const u16* __restrict__ Whh, const float* __restrict__ Sk,
    const int* __restrict__ cnt, const int* __restrict__ cols,
    const float* __restrict__ Wg2, const float* __restrict__ Sw2, const float* __restrict__ Sb2,
    u16* __restrict__ Whh2, float* __restrict__ Sk2) {
  __shared__ float wgt[4096];
  __shared__ float swt[4096];
  __shared__ float sbs[64];
  __shared__ float xl[8][64];
  int tid = threadIdx.x;
  int lane = tid & 63;
  int w = tid >> 6;  // 0..7
  int bid = blockIdx.x;
  int x = bid & 7;
  int gidx = bid >> 3;  // 0..255
  int b = x >> 1;
  int rowhalf = x & 1;
  int n = __builtin_amdgcn_readfirstlane(rowhalf * 2048 + gidx * 8 + w);
  int wid = b * NV + n;
  const u16* whhbase = Whh + (size_t)b * (NV * HD);
  int nn = __builtin_amdgcn_readfirstlane(cnt[n]);
  const int* cl = cols + n * CAP;
  int q = lane & 3;
  int gq = lane >> 2;

  // whsk2 weights -> LDS (independent; overlaps attn loads)
  for (int i = tid; i < 1024; i += 512) {
    ((float4*)wgt)[i] = ((const float4*)Wg2)[i];
    ((float4*)swt)[i] = ((const float4*)Sw2)[i];
  }
  if (tid < 64) sbs[tid] = Sb2[tid];

  const uint4* qr = (const uint4*)(whhbase + (size_t)n * HD);
  uint4 QA = qr[q];
  uint4 QB = qr[q + 4];

  float s[5], p[5];
  uint4 SA0, SB0, SA1, SB1, SA2, SB2;
#define SCORE_BLOCK(jb, SAv, SBv)                                                                \
  {                                                                                              \
    int j = (jb) * 16 + gq;                                                                      \
    int m = cl[j];                                                                               \
    const uint4* vr = (const uint4*)(whhbase + (size_t)m * HD);                                  \
    SAv = vr[q];                                                                                 \
    SBv = vr[q + 4];                                                                             \
    float t = 0.f;                                                                               \
    t = fdot2u(SAv.x, QA.x, t);                                                                  \
    t = fdot2u(SAv.y, QA.y, t);                                                                  \
    t = fdot2u(SAv.z, QA.z, t);                                                                  \
    t = fdot2u(SAv.w, QA.w, t);                                                                  \
    t = fdot2u(SBv.x, QB.x, t);                                                                  \
    t = fdot2u(SBv.y, QB.y, t);                                                                  \
    t = fdot2u(SBv.z, QB.z, t);                                                                  \
    t = fdot2u(SBv.w, QB.w, t);                                                                  \
    t += __shfl_xor(t, 1, 64);                                                                   \
    t += __shfl_xor(t, 2, 64);                                                                   \
    s[jb] = (j < nn) ? t * 0.125f : -1e30f;                                                      \
  }
  SCORE_BLOCK(0, SA0, SB0)
  SCORE_BLOCK(1, SA1, SB1)
  SCORE_BLOCK(2, SA2, SB2)
  s[3] = -1e30f;
  s[4] = -1e30f;
  bool tail = (nn > 48);
  if (tail) {
    uint4 TA, TB;
    SCORE_BLOCK(3, TA, TB)
    SCORE_BLOCK(4, TA, TB)
  }
#undef SCORE_BLOCK

  float mx = fmaxf(fmaxf(fmaxf(s[0], s[1]), fmaxf(s[2], s[3])), s[4]);
  mx = fmaxf(mx, __shfl_xor(mx, 4, 64));
  mx = fmaxf(mx, __shfl_xor(mx, 8, 64));
  mx = fmaxf(mx, __shfl_xor(mx, 16, 64));
  mx = fmaxf(mx, __shfl_xor(mx, 32, 64));
  float sum = 0.f;
#pragma unroll
  for (int jb = 0; jb < 5; ++jb) {
    p[jb] = (jb * 16 + gq < nn) ? __expf(s[jb] - mx) : 0.f;
    sum += p[jb];
  }
  sum += __shfl_xor(sum, 4, 64);
  sum += __shfl_xor(sum, 8, 64);
  sum += __shfl_xor(sum, 16, 64);
  sum += __shfl_xor(sum, 32, 64);
  float inv = 1.f / sum;

  h2 aa[8];
#pragma unroll
  for (int k = 0; k < 8; ++k) aa[k] = h2{(_Float16)0, (_Float16)0};
#define PV_ACC(pp, Av, Bv)                                                                       \
  {                                                                                              \
    _Float16 pf = (_Float16)(pp);                                                                \
    h2 ph = {pf, pf};                                                                            \
    aa[0] += __builtin_bit_cast(h2, (Av).x) * ph;                                                \
    aa[1] += __builtin_bit_cast(h2, (Av).y) * ph;                                                \
    aa[2] += __builtin_bit_cast(h2, (Av).z) * ph;                                                \
    aa[3] += __builtin_bit_cast(h2, (Av).w) * ph;                                                \
    aa[4] += __builtin_bit_cast(h2, (Bv).x) * ph;                                                \
    aa[5] += __builtin_bit_cast(h2, (Bv).y) * ph;                                                \
    aa[6] += __builtin_bit_cast(h2, (Bv).z) * ph;                                                \
    aa[7] += __builtin_bit_cast(h2, (Bv).w) * ph;                                                \
  }
  PV_ACC(p[0], SA0, SB0)
  PV_ACC(p[1], SA1, SB1)
  PV_ACC(p[2], SA2, SB2)
  if (tail) {
    int m3 = cl[48 + gq];
    const uint4* vr3 = (const uint4*)(whhbase + (size_t)m3 * HD);
    uint4 A3 = vr3[q], B3 = vr3[q + 4];
    PV_ACC(p[3], A3, B3)
    if (nn > 64) {
      int m4 = cl[64 + gq];
      const uint4* vr4 = (const uint4*)(whhbase + (size_t)m4 * HD);
      uint4 A4 = vr4[q], B4 = vr4[q + 4];
      PV_ACC(p[4], A4, B4)
    }
  }
#undef PV_ACC

  bool g1 = (gq & 1) != 0;
  h2 bb[4];
#pragma unroll
  for (int i = 0; i < 4; ++i) {
    h2 k = g1 ? aa[i + 4] : aa[i];
    h2 u = g1 ? aa[i] : aa[i + 4];
    bb[i] = k + shx(u, 4);
  }
  bool g2 = (gq & 2) != 0;
  h2 cc[2];
#pragma unroll
  for (int i = 0; i < 2; ++i) {
    h2 k = g2 ? bb[i + 2] : bb[i];
    h2 u = g2 ? bb[i] : bb[i + 2];
    cc[i] = k + shx(u, 8);
  }
  bool g4 = (gq & 4) != 0;
  h2 dd;
  {
    h2 k = g4 ? cc[1] : cc[0];
    h2 u = g4 ? cc[0] : cc[1];
    dd = k + shx(u, 16);
  }
  dd = dd + shx(dd, 32);
  int a = 8 * q + 32 * (gq & 1) + 4 * ((gq >> 1) & 1) + 2 * ((gq >> 2) & 1);
  float f0 = (float)dd[0] * inv;
  float f1 = (float)dd[1] * inv;

  float2 sk2 = *(const float2*)(Sk + (size_t)wid * HD + a);
  float o0 = (f0 > 0.f ? f0 : (__expf(f0) - 1.f)) + sk2.x;
  float o1 = (f1 > 0.f ? f1 : (__expf(f1) - 1.f)) + sk2.y;
  if ((gq & 8) == 0) {
    xl[w][a] = o0;
    xl[w][a + 1] = o1;
  }
  __syncthreads();

  // ---- whsk2 tail: 2 waves compute Whh2/Sk2 for the block's 8 rows
  if (tid < 128) {
    int cg = tid & 15;  // cols 4cg..+3
    int r = tid >> 4;   // row 0..7
    float4 aw = make_float4(0, 0, 0, 0), as = make_float4(0, 0, 0, 0);
#pragma unroll 4
    for (int k = 0; k < 64; ++k) {
      float4 wv = *(const float4*)&wgt[k * 64 + 4 * cg];
      float4 sv = *(const float4*)&swt[k * 64 + 4 * cg];
      float xv = xl[r][k];
      aw.x = fmaf(xv, wv.x, aw.x); aw.y = fmaf(xv, wv.y, aw.y);
      aw.z = fmaf(xv, wv.z, aw.z); aw.w = fmaf(xv, wv.w, aw.w);
      as.x = fmaf(xv, sv.x, as.x); as.y = fmaf(xv, sv.y, as.y);
      as.z = fmaf(xv, sv.z, as.z); as.w = fmaf(xv, sv.w, as.w);
    }
    int n_r = rowhalf * 2048 + gidx * 8 + r;
    size_t wid_r = (size_t)(b * NV + n_r) * 64 + 4 * cg;
    float4 sb4 = *(const float4*)&sbs[4 * cg];
    ushort4 hh;
    hh.x = __builtin_bit_cast(u16, (_Float16)aw.x);
    hh.y = __builtin_bit_cast(u16, (_Float16)aw.y);
    hh.z = __builtin_bit_cast(u16, (_Float16)aw.z);
    hh.w = __builtin_bit_cast(u16, (_Float16)aw.w);
    *(ushort4*)(Whh2 + wid_r) = hh;
    *(float4*)(Sk2 + wid_r) =
        make_float4(as.x + sb4.x, as.y + sb4.y, as.z + sb4.z, as.w + sb4.w);
  }
}

// ---------------- attn layer2 (r18 structure): reads Whh2/Sk2, fused readout
__global__ __launch_bounds__(256) void attn_l2_kernel(
    const u16* __restrict__ Whh, const float* __restrict__ Sk,
    const int* __restrict__ cnt, const int* __restrict__ cols,
    const float* __restrict__ roW, const float* __restrict__ rob, float* __restrict__ out) {
  int tid = threadIdx.x;
  int lane = tid & 63;
  int w = tid >> 6;
  int bid = blockIdx.x;
  int x = bid & 7;
  int gidx = bid >> 3;
  int b = x >> 1;
  int n = __builtin_amdgcn_readfirstlane((x & 1) * 2048 + gidx * 4 + w);
  int wid = b * NV + n;
  const u16* whhbase = Whh + (size_t)b * (NV * HD);
  int nn = __builtin_amdgcn_readfirstlane(cnt[n]);
  const int* cl = cols + n * CAP;
  int q = lane & 3;
  int gq = lane >> 2;

  const uint4* qr = (const uint4*)(whhbase + (size_t)n * HD);
  uint4 QA = qr[q];
  uint4 QB = qr[q + 4];

  float s[5], p[5];
  uint4 SA0, SB0, SA1, SB1, SA2, SB2;
#define SCORE_BLOCK(jb, SAv, SBv)                                                                \
  {                                                                                              \
    int j = (jb) * 16 + gq;                                                                      \
    int m = cl[j];                                                                               \
    const uint4* vr = (const uint4*)(whhbase + (size_t)m * HD);                                  \
    SAv = vr[q];                                                                                 \
    SBv = vr[q + 4];                                                                             \
    float t = 0.f;                                                                               \
    t = fdot2u(SAv.x, QA.x, t);                                                                  \
    t = fdot2u(SAv.y, QA.y, t);                                                                  \
    t = fdot2u(SAv.z, QA.z, t);                                                                  \
    t = fdot2u(SAv.w, QA.w, t);                                                                  \
    t = fdot2u(SBv.x, QB.x, t);                                                                  \
    t = fdot2u(SBv.y, QB.y, t);                                                                  \
    t = fdot2u(SBv.z, QB.z, t);                                                                  \
    t = fdot2u(SBv.w, QB.w, t);                                                                  \
    t += __shfl_xor(t, 1, 64);                                                                   \
    t += __shfl_xor(t, 2, 64);                                                                   \
    s[jb] = (j < nn) ? t * 0.125f : -1e30f;                                                      \
  }
  SCORE_BLOCK(0, SA0, SB0)
  SCORE_BLOCK(1, SA1, SB1)
  SCORE_BLOCK(2, SA2, SB2)
  s[3] = -1e30f;
  s[4] = -1e30f;
  bool tail = (nn > 48);
  if (tail) {
    uint4 TA, TB;
    SCORE_BLOCK(3, TA, TB)
    SCORE_BLOCK(4, TA, TB)
  }
#undef SCORE_BLOCK

  float mx = fmaxf(fmaxf(fmaxf(s[0], s[1]), fmaxf(s[2], s[3])), s[4]);
  mx = fmaxf(mx, __shfl_xor(mx, 4, 64));
  mx = fmaxf(mx, __shfl_xor(mx, 8, 64));
  mx = fmaxf(mx, __shfl_xor(mx, 16, 64));
  mx = fmaxf(mx, __shfl_xor(mx, 32, 64));
  float sum = 0.f;
#pragma unroll
  for (int jb = 0; jb < 5; ++jb) {
    p[jb] = (jb * 16 + gq < nn) ? __expf(s[jb] - mx) : 0.f;
    sum += p[jb];
  }
  sum += __shfl_xor(sum, 4, 64);
  sum += __shfl_xor(sum, 8, 64);
  sum += __shfl_xor(sum, 16, 64);
  sum += __shfl_xor(sum, 32, 64);
  float inv = 1.f / sum;

  h2 aa[8];
#pragma unroll
  for (int k = 0; k < 8; ++k) aa[k] = h2{(_Float16)0, (_Float16)0};
#define PV_ACC(pp, Av, Bv)                                                                       \
  {                                                                                              \
    _Float16 pf = (_Float16)(pp);                                                                \
    h2 ph = {pf, pf};                                                                            \
    aa[0] += __builtin_bit_cast(h2, (Av).x) * ph;                                                \
    aa[1] += __builtin_bit_cast(h2, (Av).y) * ph;                                                \
    aa[2] += __builtin_bit_cast(h2, (Av).z) * ph;                                                \
    aa[3] += __builtin_bit_cast(h2, (Av).w) * ph;                                                \
    aa[4] += __builtin_bit_cast(h2, (Bv).x) * ph;                                                \
    aa[5] += __builtin_bit_cast(h2, (Bv).y) * ph;                                                \
    aa[6] += __builtin_bit_cast(h2, (Bv).z) * ph;                                                \
    aa[7] += __builtin_bit_cast(h2, (Bv).w) * ph;                                                \
  }
  PV_ACC(p[0], SA0, SB0)
  PV_ACC(p[1], SA1, SB1)
  PV_ACC(p[2], SA2, SB2)
  if (tail) {
    int m3 = cl[48 + gq];
    const uint4* vr3 = (const uint4*)(whhbase + (size_t)m3 * HD);
    uint4 A3 = vr3[q], B3 = vr3[q + 4];
    PV_ACC(p[3], A3, B3)
    if (nn > 64) {
      int m4 = cl[64 + gq];
      const uint4* vr4 = (const uint4*)(whhbase + (size_t)m4 * HD);
      uint4 A4 = vr4[q], B4 = vr4[q + 4];
      PV_ACC(p[4], A4, B4)
    }
  }
#undef PV_ACC

  bool g1 = (gq & 1) != 0;
  h2 bb[4];
#pragma unroll
  for (int i = 0; i < 4; ++i) {
    h2 k = g1 ? aa[i + 4] : aa[i];
    h2 u = g1 ? aa[i] : aa[i + 4];
    bb[i] = k + shx(u, 4);
  }
  bool g2 = (gq & 2) != 0;
  h2 cc[2];
#pragma unroll
  for (int i = 0; i < 2; ++i) {
    h2 k = g2 ? bb[i + 2] : bb[i];
    h2 u = g2 ? bb[i] : bb[i + 2];
    cc[i] = k + shx(u, 8);
  }
  bool g4 = (gq & 4) != 0;
  h2 dd;
  {
    h2 k = g4 ? cc[1] : cc[0];
    h2 u = g4 ? cc[0] : cc[1];
    dd = k + shx(u, 16);
  }
  dd = dd + shx(dd, 32);
  int a = 8 * q + 32 * (gq & 1) + 4 * ((gq >> 1) & 1) + 2 * ((gq >> 2) & 1);
  float f0 = (float)dd[0] * inv;
  float f1 = (float)dd[1] * inv;

  float2 sk2 = *(const float2*)(Sk + (size_t)wid * HD + a);
  float2 ro2 = *(const float2*)(roW + a);
  float wsp = (f0 + sk2.x) * ro2.x + (f1 + sk2.y) * ro2.y;
  wsp += __shfl_xor(wsp, 1, 64);
  wsp += __shfl_xor(wsp, 2, 64);
  wsp += __shfl_xor(wsp, 4, 64);
  wsp += __shfl_xor(wsp, 8, 64);
  wsp += __shfl_xor(wsp, 16, 64);
  if (lane == 0) out[wid] = wsp + rob[0];
}

extern "C" void kernel_launch(void* const* d_in, const int* in_sizes, int n_in,
                              void* d_out, int out_size, void* d_ws, size_t ws_size,
                              hipStream_t stream) {
  const float* stim = (const float*)d_in[0];
  const float* adj  = (const float*)d_in[1];
  const float* W1   = (const float*)d_in[2];
  const float* b1   = (const float*)d_in[3];
  const float* lng  = (const float*)d_in[4];
  const float* lnb  = (const float*)d_in[5];
  const float* W2   = (const float*)d_in[6];
  const float* b2   = (const float*)d_in[7];
  const float* emb  = (const float*)d_in[8];
  const float* Wg1  = (const float*)d_in[9];
  const float* Wg2  = (const float*)d_in[10];
  const float* s1w  = (const float*)d_in[11];
  const float* s1b  = (const float*)d_in[12];
  const float* s2w  = (const float*)d_in[13];
  const float* s2b  = (const float*)d_in[14];
  const float* roW  = (const float*)d_in[15];
  const float* rob  = (const float*)d_in[16];
  float* out = (float*)d_out;

  char* ws = (char*)d_ws;
  float* part = (float*)(ws + 4096);       // 96 KB
  int*   cnt  = (int*)(ws + 131072);       // 4096 ints
  int*   cols = (int*)(ws + 147456);       // 4096*80 ints = 1.25 MB (ends 1458176)
  u16*   Whh2 = (u16*)(ws + 1572864);      // 2 MB  (layer2 f16 rows)
  float* Sk   = (float*)(ws + 5767168);    // 4 MB  (layer1 skip)
  float* Sk2  = (float*)(ws + 9961472);    // 4 MB  (layer2 skip)
  u16*   Whh  = (u16*)(ws + 14155776);     // 2 MB  (layer1 f16 rows)

  pre_kernel<<<dim3(NV + 96), dim3(256), 0, stream>>>(adj, cnt, cols, stim, W1, part);
  whsk1_kernel<<<dim3(NB * NV / 32), dim3(256), 0, stream>>>(part, b1, lng, lnb, W2, b2,
                                                             emb, Wg1, s1w, s1b, Whh, Sk);
  attn_l1_kernel<<<dim3(NB * NV / 8), dim3(512), 0, stream>>>(Whh, Sk, cnt, cols,
                                                              Wg2, s2w, s2b, Whh2, Sk2);
  attn_l2_kernel<<<dim3(NB * NV / 4), dim3(256), 0, stream>>>(Whh2, Sk2, cnt, cols,
                                                              roW, rob, out);
}